// Round 10
// baseline (255.025 us; speedup 1.0000x reference)
//
#include <hip/hip_runtime.h>
#include <math.h>

#define N 50000
#define E 800000
#define KCHEB 10
#define BT 20
#define SCAN_BLOCKS 196            // ceil(50000/256)
#define N64 ((size_t)N * 64)
#define CONV_BLOCKS 1563           // ceil((N64/8)/256)
#define COUNT_BLOCKS 3125          // E/256

typedef __attribute__((ext_vector_type(8))) short short8;   // 8 bf16 = 4 VGPRs
typedef __attribute__((ext_vector_type(4))) float f32x4;    // MFMA acc

// ---- bf16 helpers (manual, RNE) ----
__device__ __forceinline__ unsigned f2bf(float x) {
    unsigned u = __float_as_uint(x);
    return (u + 0x7FFFu + ((u >> 16) & 1u)) >> 16;
}
__device__ __forceinline__ float bf2f(unsigned h) {
    return __uint_as_float(h << 16);
}
__device__ __forceinline__ unsigned packbf(float lo, float hi) {
    return f2bf(lo) | (f2bf(hi) << 16);
}
__device__ __forceinline__ void unpack8(uint4 v, float* f) {
    f[0]=bf2f(v.x&0xFFFFu); f[1]=bf2f(v.x>>16);
    f[2]=bf2f(v.y&0xFFFFu); f[3]=bf2f(v.y>>16);
    f[4]=bf2f(v.z&0xFFFFu); f[5]=bf2f(v.z>>16);
    f[6]=bf2f(v.w&0xFFFFu); f[7]=bf2f(v.w>>16);
}
__device__ __forceinline__ uint4 pack8(const float* f) {
    return make_uint4(packbf(f[0],f[1]),packbf(f[2],f[3]),packbf(f[4],f[5]),packbf(f[6],f[7]));
}

// ---- W pack helper: [Wtop;Wbot] (128 x ncols) -> MFMA B-frags ----
__device__ __forceinline__ void pack_one(const float* Wtop, const float* Wbot,
                                         int ncols, uint4* out, int id) {
    int ntiles = ncols >> 4;
    int lane = id & 63;
    int nt = (id >> 6) % ntiles;
    int kt = id / (64 * ntiles);
    int n = nt * 16 + (lane & 15);
    int k0 = kt * 32 + (lane >> 4) * 8;
    const float* src = (k0 < 64) ? (Wtop + k0 * ncols + n) : (Wbot + (k0 - 64) * ncols + n);
    unsigned r[4];
#pragma unroll
    for (int p = 0; p < 4; p++)
        r[p] = packbf(src[(2 * p) * ncols], src[(2 * p + 1) * ncols]);
    out[id] = make_uint4(r[0], r[1], r[2], r[3]);
}

// ---------------- fused: x->bf16 convert, W-frag packs, degree count ----------
// All block groups independent; deg must be pre-zeroed (memset node).
__global__ __launch_bounds__(256) void convert_pack_count(
        const float4* __restrict__ xin, uint4* __restrict__ xbf,
        const float* __restrict__ Wd, const float* __restrict__ Wh1,
        const float* __restrict__ Whd, const float* __restrict__ Wh2,
        uint4* __restrict__ Wfrag1, uint4* __restrict__ Wfrag2,
        const int* __restrict__ row, int* __restrict__ deg) {
    int b = blockIdx.x, tid = threadIdx.x;
    if (b < CONV_BLOCKS) {
        int i = b * 256 + tid;
        if (i < (int)(N64 / 8)) {
            float4 a = xin[2 * i], c = xin[2 * i + 1];
            uint4 o;
            o.x = packbf(a.x, a.y); o.y = packbf(a.z, a.w);
            o.z = packbf(c.x, c.y); o.w = packbf(c.z, c.w);
            xbf[i] = o;
        }
    } else if (b < CONV_BLOCKS + 4) {
        int id = (b - CONV_BLOCKS) * 256 + tid;
        if (id < 1024) pack_one(Wd, Wh1, 64, Wfrag1, id);
    } else if (b < CONV_BLOCKS + 6) {
        int id = (b - CONV_BLOCKS - 4) * 256 + tid;
        if (id < 512) pack_one(Whd, Wh2, 32, Wfrag2, id);
    } else {
        int e = (b - CONV_BLOCKS - 6) * 256 + tid;
        if (e < E) atomicAdd(&deg[row[e]], 1);
    }
}

// ---------------- scan A: per-block sums ----------------
__global__ __launch_bounds__(256) void scan_a(const int* __restrict__ deg, int* __restrict__ blocksum) {
    __shared__ int sm[256];
    int t = threadIdx.x;
    int i = blockIdx.x * 256 + t;
    sm[t] = (i < N) ? deg[i] : 0;
    __syncthreads();
    for (int ofs = 128; ofs > 0; ofs >>= 1) {
        if (t < ofs) sm[t] += sm[t + ofs];
        __syncthreads();
    }
    if (t == 0) blocksum[blockIdx.x] = sm[0];
}

// ---------------- scan B (block offsets) + Bessel coeffs + kmax ----------------
// Coeff cutoff = bf16 ulp (2^-8): pipeline stores T_k in bf16; terms below the
// leading term's bf16 rounding noise are indistinguishable from quantization.
__global__ __launch_bounds__(256) void scan_b_coeffs(
        const int* __restrict__ blocksum, int* __restrict__ blockoff, int* __restrict__ rowptr,
        const float* __restrict__ tptr, float* __restrict__ coeffs, int* __restrict__ kmaxp) {
    __shared__ int sm[256];
    __shared__ float sc[KCHEB];
    int t = threadIdx.x;
    int v = (t < SCAN_BLOCKS) ? blocksum[t] : 0;
    sm[t] = v;
    __syncthreads();
    for (int ofs = 1; ofs < 256; ofs <<= 1) {
        int u = (t >= ofs) ? sm[t - ofs] : 0;
        __syncthreads();
        sm[t] += u;
        __syncthreads();
    }
    if (t < SCAN_BLOCKS) blockoff[t] = sm[t] - v;
    if (t == SCAN_BLOCKS - 1) rowptr[N] = sm[t];
    if (t < KCHEB) {
        float tt = tptr[0];
        float lt = logf(0.5f * tt);
        float s = 0.f;
        for (int m = 0; m < BT; m++) {
            float lg = lgammaf((float)m + 1.0f) + lgammaf((float)(m + t) + 1.0f);
            s += expf((2.0f * m + (float)t) * lt - lg);
        }
        float c;
        if (t == 0) c = s;
        else c = ((t & 1) == 0) ? 2.0f * s : -2.0f * s;
        coeffs[t] = c;
        sc[t] = c;
    }
    __syncthreads();
    if (t == 0) {
        float c0 = fabsf(sc[0]);
        int kmax = 1;
        for (int k = 1; k < KCHEB; k++)
            if (fabsf(sc[k]) >= 0.00390625f * c0) kmax = k;   // bf16 ulp cutoff
        kmaxp[0] = kmax;
    }
}

// ---------------- scan C (rowptr) + dinv + fillc preinit ----------------
// fillc[i] starts at rowptr[i] so fill_csr needs only ONE random access
// (the atomic) per edge instead of atomic + rowptr read.
__global__ __launch_bounds__(256) void scan_c_dinv(
        const int* __restrict__ deg, const int* __restrict__ blockoff,
        int* __restrict__ rowptr, float* __restrict__ dinv, int* __restrict__ fillc) {
    __shared__ int sm[256];
    int t = threadIdx.x;
    int i = blockIdx.x * 256 + t;
    int d = (i < N) ? deg[i] : 0;
    sm[t] = d;
    __syncthreads();
    for (int ofs = 1; ofs < 256; ofs <<= 1) {
        int u = (t >= ofs) ? sm[t - ofs] : 0;
        __syncthreads();
        sm[t] += u;
        __syncthreads();
    }
    if (i < N) {
        int rp = blockoff[blockIdx.x] + sm[t] - d;
        rowptr[i] = rp;
        fillc[i] = rp;
        dinv[i] = (d > 0) ? (1.0f / sqrtf((float)d)) : 0.0f;
    }
}

// ---------------- CSR fill: 4 independent edges/thread, phased ----------------
// fillc preinitialized to rowptr -> p = atomicAdd(&fillc[r],1) directly.
// Phase order (idx loads / atomics / writes) keeps 4 chains in flight.
__global__ __launch_bounds__(256) void fill_csr(
        const int* __restrict__ row, const int* __restrict__ col,
        int* __restrict__ fillc, const float* __restrict__ dinv,
        int2* __restrict__ edges) {
    int base = blockIdx.x * 1024 + threadIdx.x;
    int r[4], c[4], p[4];
    bool v[4];
#pragma unroll
    for (int i = 0; i < 4; i++) {
        int e = base + i * 256;
        v[i] = (e < E);
        r[i] = v[i] ? row[e] : 0;
        c[i] = v[i] ? col[e] : 0;
    }
#pragma unroll
    for (int i = 0; i < 4; i++)
        p[i] = v[i] ? atomicAdd(&fillc[r[i]], 1) : 0;
#pragma unroll
    for (int i = 0; i < 4; i++)
        if (v[i]) edges[p[i]] = make_int2(c[i] << 7, __float_as_int(dinv[r[i]] * dinv[c[i]]));
}

// ---------------- SpMM Chebyshev step, bf16 (known-good, NON-cooperative) ------
// 16 lanes/row: two 8-lane half-groups take alternating 8-edge chunks, combined
// via shfl_xor(8). Early-exits (data-driven) when k > kmax.
__global__ __launch_bounds__(256) void spmm_step(
        const int* __restrict__ rowptr, const int2* __restrict__ edges,
        const uint4* __restrict__ vin, const uint4* __restrict__ tkm2,
        uint4* __restrict__ tout, const int* __restrict__ kmaxp, int k) {
    if (k > 1 && k > kmaxp[0]) return;
    int tid = threadIdx.x;
    int lane = tid & 63;
    int lane8 = lane & 7;
    int gbase = lane & 56;             // base lane of this 8-lane half-group
    int h = (lane >> 3) & 1;           // chunk parity
    int r = blockIdx.x * 16 + (tid >> 6) * 4 + (lane >> 4);
    int jb = rowptr[r], je = rowptr[r + 1];
    const char* vbase = (const char*)vin;
    int myoff16 = lane8 * 16;
    float a0=0,a1=0,a2=0,a3=0,a4=0,a5=0,a6=0,a7=0;
    for (int j0 = jb + h * 8; j0 < je; j0 += 16) {
        int jj = j0 + lane8;
        int myoff = 0; float myw = 0.f;
        if (jj < je) { int2 e = edges[jj]; myoff = e.x; myw = __int_as_float(e.y); }
#pragma unroll
        for (int i = 0; i < 8; i++) {
            int off = __shfl(myoff, gbase + i, 64);
            float w = __shfl(myw, gbase + i, 64);
            uint4 v = *(const uint4*)(vbase + off + myoff16);
            a0 = fmaf(w, bf2f(v.x & 0xFFFFu), a0);
            a1 = fmaf(w, bf2f(v.x >> 16),     a1);
            a2 = fmaf(w, bf2f(v.y & 0xFFFFu), a2);
            a3 = fmaf(w, bf2f(v.y >> 16),     a3);
            a4 = fmaf(w, bf2f(v.z & 0xFFFFu), a4);
            a5 = fmaf(w, bf2f(v.z >> 16),     a5);
            a6 = fmaf(w, bf2f(v.w & 0xFFFFu), a6);
            a7 = fmaf(w, bf2f(v.w >> 16),     a7);
        }
    }
    a0 += __shfl_xor(a0, 8, 64);
    a1 += __shfl_xor(a1, 8, 64);
    a2 += __shfl_xor(a2, 8, 64);
    a3 += __shfl_xor(a3, 8, 64);
    a4 += __shfl_xor(a4, 8, 64);
    a5 += __shfl_xor(a5, 8, 64);
    a6 += __shfl_xor(a6, 8, 64);
    a7 += __shfl_xor(a7, 8, 64);
    if (h == 0) {
        float s0=-a0,s1=-a1,s2=-a2,s3=-a3,s4=-a4,s5=-a5,s6=-a6,s7=-a7;
        int idx = r * 8 + lane8;
        if (k >= 2) {
            uint4 tm = tkm2[idx];
            s0 = 2.f*s0 - bf2f(tm.x & 0xFFFFu);
            s1 = 2.f*s1 - bf2f(tm.x >> 16);
            s2 = 2.f*s2 - bf2f(tm.y & 0xFFFFu);
            s3 = 2.f*s3 - bf2f(tm.y >> 16);
            s4 = 2.f*s4 - bf2f(tm.z & 0xFFFFu);
            s5 = 2.f*s5 - bf2f(tm.z >> 16);
            s6 = 2.f*s6 - bf2f(tm.w & 0xFFFFu);
            s7 = 2.f*s7 - bf2f(tm.w >> 16);
        }
        uint4 o;
        o.x = packbf(s0, s1); o.y = packbf(s2, s3);
        o.z = packbf(s4, s5); o.w = packbf(s6, s7);
        tout[idx] = o;
    }
}

// ---------------- MFMA matmul: hidden = relu([base|heat] @ Bfrag), 64 cols ------
__global__ __launch_bounds__(256) void matmul_hidden(
        const unsigned short* __restrict__ basebf, const unsigned short* __restrict__ Tall,
        int nslots, const float* __restrict__ coeffs, const int* __restrict__ kmaxp,
        const uint4* __restrict__ Wfrag, unsigned short* __restrict__ hidbf) {
    __shared__ __align__(16) unsigned short At[64][136];   // pad 8 -> row stride 272B
    int tid = threadIdx.x;
    int row0 = blockIdx.x * 64;
    int kmax = kmaxp[0]; if (kmax > KCHEB - 1) kmax = KCHEB - 1;
    float c0 = coeffs[0];
    for (int u = tid; u < 1024; u += 256) {
        int rr = u >> 4, seg = u & 15;
        int r = row0 + rr;
        uint4 val = make_uint4(0, 0, 0, 0);
        int col;
        if (seg < 8) {
            col = seg * 8;
            if (r < N) val = *(const uint4*)(basebf + (size_t)r * 64 + seg * 8);
        } else {
            int s = seg - 8;
            col = 64 + s * 8;
            if (r < N) {
                uint4 xv = *(const uint4*)(basebf + (size_t)r * 64 + s * 8);
                float h[8], f[8];
                unpack8(xv, f);
#pragma unroll
                for (int q = 0; q < 8; q++) h[q] = c0 * f[q];
                for (int j = 1; j <= kmax; j++) {
                    const unsigned short* Tj = Tall + (size_t)((j - 1) % nslots) * N64;
                    uint4 tv = *(const uint4*)(Tj + (size_t)r * 64 + s * 8);
                    float g[8];
                    unpack8(tv, g);
                    float cj = coeffs[j];
#pragma unroll
                    for (int q = 0; q < 8; q++) h[q] = fmaf(cj, g[q], h[q]);
                }
                val = pack8(h);
            }
        }
        *(uint4*)&At[rr][col] = val;
    }
    __syncthreads();
    int wv = tid >> 6, lane = tid & 63;
    int m0 = wv * 16;
    short8 afr[4];
#pragma unroll
    for (int kt = 0; kt < 4; kt++)
        afr[kt] = *(const short8*)&At[m0 + (lane & 15)][kt * 32 + (lane >> 4) * 8];
    f32x4 acc[4];
#pragma unroll
    for (int nt = 0; nt < 4; nt++) acc[nt] = (f32x4){0.f, 0.f, 0.f, 0.f};
#pragma unroll
    for (int nt = 0; nt < 4; nt++) {
#pragma unroll
        for (int kt = 0; kt < 4; kt++) {
            short8 bfr = *(const short8*)&Wfrag[kt * 256 + nt * 64 + lane];
            acc[nt] = __builtin_amdgcn_mfma_f32_16x16x32_bf16(afr[kt], bfr, acc[nt], 0, 0, 0);
        }
    }
#pragma unroll
    for (int nt = 0; nt < 4; nt++) {
#pragma unroll
        for (int i = 0; i < 4; i++) {
            int r = row0 + m0 + (lane >> 4) * 4 + i;
            if (r < N)
                hidbf[(size_t)r * 64 + nt * 16 + (lane & 15)] =
                    (unsigned short)f2bf(fmaxf(acc[nt][i], 0.f));
        }
    }
}

// ---------------- MFMA matmul + log_softmax: out = lsm([hid|heat2] @ Bfrag) ----
__global__ __launch_bounds__(256) void matmul_out(
        const unsigned short* __restrict__ basebf, const unsigned short* __restrict__ Tall,
        int nslots, const float* __restrict__ coeffs, const int* __restrict__ kmaxp,
        const uint4* __restrict__ Wfrag, float* __restrict__ out) {
    __shared__ __align__(16) unsigned short At[64][136];
    int tid = threadIdx.x;
    int row0 = blockIdx.x * 64;
    int kmax = kmaxp[0]; if (kmax > KCHEB - 1) kmax = KCHEB - 1;
    float c0 = coeffs[0];
    for (int u = tid; u < 1024; u += 256) {
        int rr = u >> 4, seg = u & 15;
        int r = row0 + rr;
        uint4 val = make_uint4(0, 0, 0, 0);
        int col;
        if (seg < 8) {
            col = seg * 8;
            if (r < N) val = *(const uint4*)(basebf + (size_t)r * 64 + seg * 8);
        } else {
            int s = seg - 8;
            col = 64 + s * 8;
            if (r < N) {
                uint4 xv = *(const uint4*)(basebf + (size_t)r * 64 + s * 8);
                float h[8], f[8];
                unpack8(xv, f);
#pragma unroll
                for (int q = 0; q < 8; q++) h[q] = c0 * f[q];
                for (int j = 1; j <= kmax; j++) {
                    const unsigned short* Tj = Tall + (size_t)((j - 1) % nslots) * N64;
                    uint4 tv = *(const uint4*)(Tj + (size_t)r * 64 + s * 8);
                    float g[8];
                    unpack8(tv, g);
                    float cj = coeffs[j];
#pragma unroll
                    for (int q = 0; q < 8; q++) h[q] = fmaf(cj, g[q], h[q]);
                }
                val = pack8(h);
            }
        }
        *(uint4*)&At[rr][col] = val;
    }
    __syncthreads();
    int wv = tid >> 6, lane = tid & 63;
    int m0 = wv * 16;
    short8 afr[4];
#pragma unroll
    for (int kt = 0; kt < 4; kt++)
        afr[kt] = *(const short8*)&At[m0 + (lane & 15)][kt * 32 + (lane >> 4) * 8];
    f32x4 acc[2];
    acc[0] = (f32x4){0.f, 0.f, 0.f, 0.f};
    acc[1] = (f32x4){0.f, 0.f, 0.f, 0.f};
#pragma unroll
    for (int nt = 0; nt < 2; nt++) {
#pragma unroll
        for (int kt = 0; kt < 4; kt++) {
            short8 bfr = *(const short8*)&Wfrag[kt * 128 + nt * 64 + lane];
            acc[nt] = __builtin_amdgcn_mfma_f32_16x16x32_bf16(afr[kt], bfr, acc[nt], 0, 0, 0);
        }
    }
#pragma unroll
    for (int i = 0; i < 4; i++) {
        float f0 = acc[0][i], f1 = acc[1][i];
        float m = fmaxf(f0, f1);
#pragma unroll
        for (int o = 1; o < 16; o <<= 1) m = fmaxf(m, __shfl_xor(m, o, 64));
        float s = expf(f0 - m) + expf(f1 - m);
#pragma unroll
        for (int o = 1; o < 16; o <<= 1) s += __shfl_xor(s, o, 64);
        float ls = m + logf(s);
        int r = row0 + m0 + (lane >> 4) * 4 + i;
        if (r < N) {
            out[(size_t)r * 32 + (lane & 15)] = f0 - ls;
            out[(size_t)r * 32 + 16 + (lane & 15)] = f1 - ls;
        }
    }
}

extern "C" void kernel_launch(void* const* d_in, const int* in_sizes, int n_in,
                              void* d_out, int out_size, void* d_ws, size_t ws_size,
                              hipStream_t stream) {
    const float* x   = (const float*)d_in[0];
    const int*   ei  = (const int*)d_in[1];
    const float* Wd  = (const float*)d_in[2];
    const float* Wh1 = (const float*)d_in[3];
    const float* Whd = (const float*)d_in[4];
    const float* Wh2 = (const float*)d_in[5];
    const float* tp  = (const float*)d_in[6];
    const int* row = ei;
    const int* col = ei + E;

    size_t off = 0;
    auto alloc = [&](size_t bytes) -> void* {
        void* p = (char*)d_ws + off;
        off += (bytes + 255) & ~(size_t)255;
        return p;
    };
    int*   deg      = (int*)alloc((size_t)N * 4);
    int*   fillc    = (int*)alloc((size_t)N * 4);
    int*   rowptr   = (int*)alloc((size_t)(N + 1) * 4);
    float* dinv     = (float*)alloc((size_t)N * 4);
    float* coeffs   = (float*)alloc(KCHEB * 4);
    int*   kmaxp    = (int*)alloc(4);
    int*   blocksum = (int*)alloc(SCAN_BLOCKS * 4);
    int*   blockoff = (int*)alloc(SCAN_BLOCKS * 4);
    int2*  edges    = (int2*)alloc((size_t)E * 8);
    unsigned short* xbf   = (unsigned short*)alloc(N64 * 2);
    unsigned short* hidbf = (unsigned short*)alloc(N64 * 2);
    uint4* Wfrag1   = (uint4*)alloc(1024 * 16);
    uint4* Wfrag2   = (uint4*)alloc(512 * 16);
    size_t tbytes = N64 * 2;   // already 256-aligned
    int nslots = (int)((ws_size - off) / tbytes);
    if (nslots > KCHEB - 1) nslots = KCHEB - 1;
    if (nslots < 1) nslots = 1;
    unsigned short* Tall = (unsigned short*)alloc((size_t)nslots * tbytes);
    auto Tslot = [&](int k) -> unsigned short* {
        return (unsigned short*)((char*)Tall + (size_t)((k - 1) % nslots) * tbytes);
    };

    hipMemsetAsync(deg, 0, (size_t)N * 4, stream);

    convert_pack_count<<<CONV_BLOCKS + 6 + COUNT_BLOCKS, 256, 0, stream>>>(
        (const float4*)x, (uint4*)xbf, Wd, Wh1, Whd, Wh2, Wfrag1, Wfrag2, row, deg);
    scan_a<<<SCAN_BLOCKS, 256, 0, stream>>>(deg, blocksum);
    scan_b_coeffs<<<1, 256, 0, stream>>>(blocksum, blockoff, rowptr, tp, coeffs, kmaxp);
    scan_c_dinv<<<SCAN_BLOCKS, 256, 0, stream>>>(deg, blockoff, rowptr, dinv, fillc);
    fill_csr<<<(E + 1023) / 1024, 256, 0, stream>>>(row, col, fillc, dinv, edges);

    const int spmm_grid = N / 16;   // 3125: 16 rows/block (16 lanes/row)
    const int mm_grid = (N + 63) / 64;

    // ---- heat phase 1: base = x (bf16) ----
    for (int k = 1; k < KCHEB; k++) {
        const uint4* vin = (k == 1) ? (const uint4*)xbf : (const uint4*)Tslot(k - 1);
        const uint4* tm2 = (k <= 2) ? (const uint4*)xbf : (const uint4*)Tslot(k - 2);
        spmm_step<<<spmm_grid, 256, 0, stream>>>(rowptr, edges, vin, tm2,
                                                 (uint4*)Tslot(k), kmaxp, k);
    }
    matmul_hidden<<<mm_grid, 256, 0, stream>>>(xbf, Tall, nslots, coeffs, kmaxp, Wfrag1, hidbf);

    // ---- heat phase 2: base = hidden (bf16) ----
    for (int k = 1; k < KCHEB; k++) {
        const uint4* vin = (k == 1) ? (const uint4*)hidbf : (const uint4*)Tslot(k - 1);
        const uint4* tm2 = (k <= 2) ? (const uint4*)hidbf : (const uint4*)Tslot(k - 2);
        spmm_step<<<spmm_grid, 256, 0, stream>>>(rowptr, edges, vin, tm2,
                                                 (uint4*)Tslot(k), kmaxp, k);
    }
    matmul_out<<<mm_grid, 256, 0, stream>>>(hidbf, Tall, nslots, coeffs, kmaxp, Wfrag2, (float*)d_out);
}

// Round 11
// 220.600 us; speedup vs baseline: 1.1560x; 1.1560x over previous
//
#include <hip/hip_runtime.h>
#include <math.h>

#define N 50000
#define E 800000
#define KCHEB 10
#define BT 20
#define N64 ((size_t)N * 64)
#define UROW ((size_t)(N + 1) * 64)    // u-arrays have a zeroed pad row N
#define CONV_BLOCKS 1563               // ceil((N64/8)/256)
#define FILL_BLOCKS 3125               // E/256
#define XU_BLOCKS 1563                 // ceil((N64/8 + 8)/256)
#define PAD_BLOCKS 196                 // ceil(N/256)

typedef __attribute__((ext_vector_type(8))) short short8;   // 8 bf16 = 4 VGPRs
typedef __attribute__((ext_vector_type(4))) float f32x4;    // MFMA acc

// ---- bf16 helpers (manual, RNE) ----
__device__ __forceinline__ unsigned f2bf(float x) {
    unsigned u = __float_as_uint(x);
    return (u + 0x7FFFu + ((u >> 16) & 1u)) >> 16;
}
__device__ __forceinline__ float bf2f(unsigned h) {
    return __uint_as_float(h << 16);
}
__device__ __forceinline__ unsigned packbf(float lo, float hi) {
    return f2bf(lo) | (f2bf(hi) << 16);
}
__device__ __forceinline__ void unpack8(uint4 v, float* f) {
    f[0]=bf2f(v.x&0xFFFFu); f[1]=bf2f(v.x>>16);
    f[2]=bf2f(v.y&0xFFFFu); f[3]=bf2f(v.y>>16);
    f[4]=bf2f(v.z&0xFFFFu); f[5]=bf2f(v.z>>16);
    f[6]=bf2f(v.w&0xFFFFu); f[7]=bf2f(v.w>>16);
}
__device__ __forceinline__ uint4 pack8(const float* f) {
    return make_uint4(packbf(f[0],f[1]),packbf(f[2],f[3]),packbf(f[4],f[5]),packbf(f[6],f[7]));
}

// ---- W pack helper: [Wtop;Wbot] (128 x ncols) -> MFMA B-frags ----
__device__ __forceinline__ void pack_one(const float* Wtop, const float* Wbot,
                                         int ncols, uint4* out, int id) {
    int ntiles = ncols >> 4;
    int lane = id & 63;
    int nt = (id >> 6) % ntiles;
    int kt = id / (64 * ntiles);
    int n = nt * 16 + (lane & 15);
    int k0 = kt * 32 + (lane >> 4) * 8;
    const float* src = (k0 < 64) ? (Wtop + k0 * ncols + n) : (Wbot + (k0 - 64) * ncols + n);
    unsigned r[4];
#pragma unroll
    for (int p = 0; p < 4; p++)
        r[p] = packbf(src[(2 * p) * ncols], src[(2 * p + 1) * ncols]);
    out[id] = make_uint4(r[0], r[1], r[2], r[3]);
}

// ---------------- K1: ELL fill (single pass) + x->bf16 + W-frag packs ----------
// Fill blocks FIRST so the latency-bound scatter starts immediately and the
// streaming conversion fills the bubbles. deg pre-zeroed by memset node.
// ELL: 64 slots/row (P(deg>64) ~ 1e-14 for Binom(800k, 1/50k); guarded).
__global__ __launch_bounds__(256) void k1_fill_convert_pack(
        const int* __restrict__ row, const int* __restrict__ col,
        int* __restrict__ deg, int* __restrict__ ell,
        const float4* __restrict__ xin, uint4* __restrict__ xbf,
        const float* __restrict__ Wd, const float* __restrict__ Wh1,
        const float* __restrict__ Whd, const float* __restrict__ Wh2,
        uint4* __restrict__ Wfrag1, uint4* __restrict__ Wfrag2) {
    int b = blockIdx.x, tid = threadIdx.x;
    if (b < FILL_BLOCKS) {
        int e = b * 256 + tid;
        if (e < E) {
            int r = row[e], c = col[e];
            int slot = atomicAdd(&deg[r], 1);
            if (slot < 64) ell[(size_t)r * 64 + slot] = c << 7;   // byte offset into u
        }
    } else if (b < FILL_BLOCKS + CONV_BLOCKS) {
        int i = (b - FILL_BLOCKS) * 256 + tid;
        if (i < (int)(N64 / 8)) {
            float4 a = xin[2 * i], c = xin[2 * i + 1];
            uint4 o;
            o.x = packbf(a.x, a.y); o.y = packbf(a.z, a.w);
            o.z = packbf(c.x, c.y); o.w = packbf(c.z, c.w);
            xbf[i] = o;
        }
    } else if (b < FILL_BLOCKS + CONV_BLOCKS + 4) {
        int id = (b - FILL_BLOCKS - CONV_BLOCKS) * 256 + tid;
        if (id < 1024) pack_one(Wd, Wh1, 64, Wfrag1, id);
    } else {
        int id = (b - FILL_BLOCKS - CONV_BLOCKS - 4) * 256 + tid;
        if (id < 512) pack_one(Whd, Wh2, 32, Wfrag2, id);
    }
}

// ---------------- K2: dinv + xu + ELL pad + slot pad-row zero + coeffs ---------
// xu = bf16(dinv .* x) with zero row N (gather pad target). ELL rows padded to
// a multiple of 8 with offset N<<7 so spmm's inner unroll is branch-free.
// Coeff cutoff = bf16 ulp (2^-8): terms below the leading term's bf16 rounding
// noise are indistinguishable from quantization already in the pipeline.
__global__ __launch_bounds__(256) void k2_node(
        const float* __restrict__ x, const int* __restrict__ deg,
        float* __restrict__ dinv, unsigned short* __restrict__ xu,
        int* __restrict__ ell, unsigned short* __restrict__ Uarr,
        unsigned short* __restrict__ hidu, int nslots,
        const float* __restrict__ tptr, float* __restrict__ coeffs,
        int* __restrict__ kmaxp) {
    __shared__ float sc[KCHEB];
    int b = blockIdx.x, tid = threadIdx.x;
    if (b < XU_BLOCKS) {
        int i = b * 256 + tid;                 // uint4 index into xu
        if (i < (int)(N64 / 8)) {
            int r = i >> 3, sub = i & 7;
            int d = deg[r];
            float dr = (d > 0) ? rsqrtf((float)d) : 0.f;
            const float* xp = x + (size_t)r * 64 + sub * 8;
            float4 a = *(const float4*)xp, c = *(const float4*)(xp + 4);
            float f[8] = {dr*a.x, dr*a.y, dr*a.z, dr*a.w, dr*c.x, dr*c.y, dr*c.z, dr*c.w};
            ((uint4*)xu)[i] = pack8(f);
            if (sub == 0) dinv[r] = dr;
        } else if (i < (int)(N64 / 8) + 8) {
            ((uint4*)xu)[i] = make_uint4(0, 0, 0, 0);   // row N = 0
        }
    } else if (b < XU_BLOCKS + PAD_BLOCKS) {
        int r = (b - XU_BLOCKS) * 256 + tid;
        if (r < N) {
            int d = deg[r]; if (d > 64) d = 64;
            int dpad = (d + 7) & ~7;
            for (int j = d; j < dpad; j++) ell[(size_t)r * 64 + j] = (N << 7);
        }
    } else if (b == XU_BLOCKS + PAD_BLOCKS) {
        int total = (nslots + 1) * 8;          // nslots u-rows + hidu row, 8 uint4 each
        if (tid < total) {
            int which = tid >> 3, q = tid & 7;
            uint4* dst = (which < nslots)
                ? (uint4*)(Uarr + (size_t)which * UROW + (size_t)N * 64)
                : (uint4*)(hidu + (size_t)N * 64);
            dst[q] = make_uint4(0, 0, 0, 0);
        }
    } else {
        int v = tid;
        if (v < KCHEB) {
            float tt = tptr[0];
            float lt = logf(0.5f * tt);
            float s = 0.f;
            for (int m = 0; m < BT; m++) {
                float lg = lgammaf((float)m + 1.0f) + lgammaf((float)(m + v) + 1.0f);
                s += expf((2.0f * m + (float)v) * lt - lg);
            }
            float c;
            if (v == 0) c = s;
            else c = ((v & 1) == 0) ? 2.0f * s : -2.0f * s;
            coeffs[v] = c;
            sc[v] = c;
        }
        __syncthreads();
        if (v == 0) {
            float c0 = fabsf(sc[0]);
            int kmax = 1;
            for (int k = 1; k < KCHEB; k++)
                if (fabsf(sc[k]) >= 0.00390625f * c0) kmax = k;   // bf16 ulp cutoff
            kmaxp[0] = kmax;
        }
    }
}

// ---------------- SpMM Chebyshev step (ELL, pre-scaled, weight-free) -----------
// 16 lanes/row: two 8-lane half-groups take alternating 8-edge chunks of the
// padded ELL row, combined via shfl_xor(8). Gathers the dinv-pre-scaled u
// vector; applies -dinv[r] in the epilogue (w = dinv[r]*dinv[c] separable).
// Writes T_k (unscaled, for recurrence + heat) and u_k = dinv.*T_k (next gather).
__global__ __launch_bounds__(256) void spmm_step(
        const int* __restrict__ deg, const int* __restrict__ ell,
        const unsigned short* __restrict__ baseu, const unsigned short* __restrict__ baseT,
        unsigned short* __restrict__ Tarr, unsigned short* __restrict__ Uarr,
        int nslots, const float* __restrict__ dinv,
        const int* __restrict__ kmaxp, int k) {
    if (k > 1 && k > kmaxp[0]) return;
    const unsigned short* uin = (k == 1) ? baseu
                              : Uarr + (size_t)((k - 2) % nslots) * UROW;
    const uint4* tkm2 = (const uint4*)((k <= 2) ? baseT
                              : Tarr + (size_t)((k - 3) % nslots) * N64);
    uint4* Tout = (uint4*)(Tarr + (size_t)((k - 1) % nslots) * N64);
    uint4* Uout = (uint4*)(Uarr + (size_t)((k - 1) % nslots) * UROW);
    int tid = threadIdx.x;
    int lane = tid & 63;
    int lane8 = lane & 7;
    int gbase = lane & 56;
    int h = (lane >> 3) & 1;
    int r = blockIdx.x * 16 + (tid >> 6) * 4 + (lane >> 4);
    int d = deg[r]; if (d > 64) d = 64;
    int dpad = (d + 7) & ~7;
    const int* erow = ell + (size_t)r * 64;
    const char* vbase = (const char*)uin;
    int myoff16 = lane8 * 16;
    float a0=0,a1=0,a2=0,a3=0,a4=0,a5=0,a6=0,a7=0;
    for (int j0 = h * 8; j0 < dpad; j0 += 16) {
        int myoff = erow[j0 + lane8];     // pads -> row N (zeros)
#pragma unroll
        for (int i = 0; i < 8; i++) {
            int off = __shfl(myoff, gbase + i, 64);
            uint4 v = *(const uint4*)(vbase + off + myoff16);
            a0 += bf2f(v.x & 0xFFFFu);
            a1 += bf2f(v.x >> 16);
            a2 += bf2f(v.y & 0xFFFFu);
            a3 += bf2f(v.y >> 16);
            a4 += bf2f(v.z & 0xFFFFu);
            a5 += bf2f(v.z >> 16);
            a6 += bf2f(v.w & 0xFFFFu);
            a7 += bf2f(v.w >> 16);
        }
    }
    a0 += __shfl_xor(a0, 8, 64);
    a1 += __shfl_xor(a1, 8, 64);
    a2 += __shfl_xor(a2, 8, 64);
    a3 += __shfl_xor(a3, 8, 64);
    a4 += __shfl_xor(a4, 8, 64);
    a5 += __shfl_xor(a5, 8, 64);
    a6 += __shfl_xor(a6, 8, 64);
    a7 += __shfl_xor(a7, 8, 64);
    if (h == 0) {
        float dr = dinv[r];
        float ndr = -dr;
        float s0=ndr*a0, s1=ndr*a1, s2=ndr*a2, s3=ndr*a3;
        float s4=ndr*a4, s5=ndr*a5, s6=ndr*a6, s7=ndr*a7;
        int idx = r * 8 + lane8;
        if (k >= 2) {
            uint4 tm = tkm2[idx];
            s0 = 2.f*s0 - bf2f(tm.x & 0xFFFFu);
            s1 = 2.f*s1 - bf2f(tm.x >> 16);
            s2 = 2.f*s2 - bf2f(tm.y & 0xFFFFu);
            s3 = 2.f*s3 - bf2f(tm.y >> 16);
            s4 = 2.f*s4 - bf2f(tm.z & 0xFFFFu);
            s5 = 2.f*s5 - bf2f(tm.z >> 16);
            s6 = 2.f*s6 - bf2f(tm.w & 0xFFFFu);
            s7 = 2.f*s7 - bf2f(tm.w >> 16);
        }
        float t8[8] = {s0,s1,s2,s3,s4,s5,s6,s7};
        Tout[idx] = pack8(t8);
        float u8[8] = {dr*s0,dr*s1,dr*s2,dr*s3,dr*s4,dr*s5,dr*s6,dr*s7};
        Uout[idx] = pack8(u8);
    }
}

// ---------------- MFMA matmul: hidden = relu([base|heat] @ Bfrag), 64 cols ------
// Also emits hidu = bf16(dinv .* hidden) as phase-2's pre-scaled gather source.
__global__ __launch_bounds__(256) void matmul_hidden(
        const unsigned short* __restrict__ basebf, const unsigned short* __restrict__ Tarr,
        int nslots, const float* __restrict__ coeffs, const int* __restrict__ kmaxp,
        const uint4* __restrict__ Wfrag, unsigned short* __restrict__ hidbf,
        const float* __restrict__ dinv, unsigned short* __restrict__ hidu) {
    __shared__ __align__(16) unsigned short At[64][136];   // pad 8 -> row stride 272B
    int tid = threadIdx.x;
    int row0 = blockIdx.x * 64;
    int kmax = kmaxp[0]; if (kmax > KCHEB - 1) kmax = KCHEB - 1;
    float c0 = coeffs[0];
    for (int u = tid; u < 1024; u += 256) {
        int rr = u >> 4, seg = u & 15;
        int r = row0 + rr;
        uint4 val = make_uint4(0, 0, 0, 0);
        int col;
        if (seg < 8) {
            col = seg * 8;
            if (r < N) val = *(const uint4*)(basebf + (size_t)r * 64 + seg * 8);
        } else {
            int s = seg - 8;
            col = 64 + s * 8;
            if (r < N) {
                uint4 xv = *(const uint4*)(basebf + (size_t)r * 64 + s * 8);
                float h[8], f[8];
                unpack8(xv, f);
#pragma unroll
                for (int q = 0; q < 8; q++) h[q] = c0 * f[q];
                for (int j = 1; j <= kmax; j++) {
                    const unsigned short* Tj = Tarr + (size_t)((j - 1) % nslots) * N64;
                    uint4 tv = *(const uint4*)(Tj + (size_t)r * 64 + s * 8);
                    float g[8];
                    unpack8(tv, g);
                    float cj = coeffs[j];
#pragma unroll
                    for (int q = 0; q < 8; q++) h[q] = fmaf(cj, g[q], h[q]);
                }
                val = pack8(h);
            }
        }
        *(uint4*)&At[rr][col] = val;
    }
    __syncthreads();
    int wv = tid >> 6, lane = tid & 63;
    int m0 = wv * 16;
    short8 afr[4];
#pragma unroll
    for (int kt = 0; kt < 4; kt++)
        afr[kt] = *(const short8*)&At[m0 + (lane & 15)][kt * 32 + (lane >> 4) * 8];
    f32x4 acc[4];
#pragma unroll
    for (int nt = 0; nt < 4; nt++) acc[nt] = (f32x4){0.f, 0.f, 0.f, 0.f};
#pragma unroll
    for (int nt = 0; nt < 4; nt++) {
#pragma unroll
        for (int kt = 0; kt < 4; kt++) {
            short8 bfr = *(const short8*)&Wfrag[kt * 256 + nt * 64 + lane];
            acc[nt] = __builtin_amdgcn_mfma_f32_16x16x32_bf16(afr[kt], bfr, acc[nt], 0, 0, 0);
        }
    }
    float drow[4];
#pragma unroll
    for (int i = 0; i < 4; i++) {
        int r = row0 + m0 + (lane >> 4) * 4 + i;
        drow[i] = (r < N) ? dinv[r] : 0.f;
    }
#pragma unroll
    for (int nt = 0; nt < 4; nt++) {
#pragma unroll
        for (int i = 0; i < 4; i++) {
            int r = row0 + m0 + (lane >> 4) * 4 + i;
            if (r < N) {
                float hv = fmaxf(acc[nt][i], 0.f);
                size_t o = (size_t)r * 64 + nt * 16 + (lane & 15);
                hidbf[o] = (unsigned short)f2bf(hv);
                hidu[o]  = (unsigned short)f2bf(drow[i] * hv);
            }
        }
    }
}

// ---------------- MFMA matmul + log_softmax: out = lsm([hid|heat2] @ Bfrag) ----
__global__ __launch_bounds__(256) void matmul_out(
        const unsigned short* __restrict__ basebf, const unsigned short* __restrict__ Tarr,
        int nslots, const float* __restrict__ coeffs, const int* __restrict__ kmaxp,
        const uint4* __restrict__ Wfrag, float* __restrict__ out) {
    __shared__ __align__(16) unsigned short At[64][136];
    int tid = threadIdx.x;
    int row0 = blockIdx.x * 64;
    int kmax = kmaxp[0]; if (kmax > KCHEB - 1) kmax = KCHEB - 1;
    float c0 = coeffs[0];
    for (int u = tid; u < 1024; u += 256) {
        int rr = u >> 4, seg = u & 15;
        int r = row0 + rr;
        uint4 val = make_uint4(0, 0, 0, 0);
        int col;
        if (seg < 8) {
            col = seg * 8;
            if (r < N) val = *(const uint4*)(basebf + (size_t)r * 64 + seg * 8);
        } else {
            int s = seg - 8;
            col = 64 + s * 8;
            if (r < N) {
                uint4 xv = *(const uint4*)(basebf + (size_t)r * 64 + s * 8);
                float h[8], f[8];
                unpack8(xv, f);
#pragma unroll
                for (int q = 0; q < 8; q++) h[q] = c0 * f[q];
                for (int j = 1; j <= kmax; j++) {
                    const unsigned short* Tj = Tarr + (size_t)((j - 1) % nslots) * N64;
                    uint4 tv = *(const uint4*)(Tj + (size_t)r * 64 + s * 8);
                    float g[8];
                    unpack8(tv, g);
                    float cj = coeffs[j];
#pragma unroll
                    for (int q = 0; q < 8; q++) h[q] = fmaf(cj, g[q], h[q]);
                }
                val = pack8(h);
            }
        }
        *(uint4*)&At[rr][col] = val;
    }
    __syncthreads();
    int wv = tid >> 6, lane = tid & 63;
    int m0 = wv * 16;
    short8 afr[4];
#pragma unroll
    for (int kt = 0; kt < 4; kt++)
        afr[kt] = *(const short8*)&At[m0 + (lane & 15)][kt * 32 + (lane >> 4) * 8];
    f32x4 acc[2];
    acc[0] = (f32x4){0.f, 0.f, 0.f, 0.f};
    acc[1] = (f32x4){0.f, 0.f, 0.f, 0.f};
#pragma unroll
    for (int nt = 0; nt < 2; nt++) {
#pragma unroll
        for (int kt = 0; kt < 4; kt++) {
            short8 bfr = *(const short8*)&Wfrag[kt * 128 + nt * 64 + lane];
            acc[nt] = __builtin_amdgcn_mfma_f32_16x16x32_bf16(afr[kt], bfr, acc[nt], 0, 0, 0);
        }
    }
#pragma unroll
    for (int i = 0; i < 4; i++) {
        float f0 = acc[0][i], f1 = acc[1][i];
        float m = fmaxf(f0, f1);
#pragma unroll
        for (int o = 1; o < 16; o <<= 1) m = fmaxf(m, __shfl_xor(m, o, 64));
        float s = expf(f0 - m) + expf(f1 - m);
#pragma unroll
        for (int o = 1; o < 16; o <<= 1) s += __shfl_xor(s, o, 64);
        float ls = m + logf(s);
        int r = row0 + m0 + (lane >> 4) * 4 + i;
        if (r < N) {
            out[(size_t)r * 32 + (lane & 15)] = f0 - ls;
            out[(size_t)r * 32 + 16 + (lane & 15)] = f1 - ls;
        }
    }
}

extern "C" void kernel_launch(void* const* d_in, const int* in_sizes, int n_in,
                              void* d_out, int out_size, void* d_ws, size_t ws_size,
                              hipStream_t stream) {
    const float* x   = (const float*)d_in[0];
    const int*   ei  = (const int*)d_in[1];
    const float* Wd  = (const float*)d_in[2];
    const float* Wh1 = (const float*)d_in[3];
    const float* Whd = (const float*)d_in[4];
    const float* Wh2 = (const float*)d_in[5];
    const float* tp  = (const float*)d_in[6];
    const int* row = ei;
    const int* col = ei + E;

    size_t off = 0;
    auto alloc = [&](size_t bytes) -> void* {
        void* p = (char*)d_ws + off;
        off += (bytes + 255) & ~(size_t)255;
        return p;
    };
    int*   deg    = (int*)alloc((size_t)N * 4);
    float* dinv   = (float*)alloc((size_t)N * 4);
    float* coeffs = (float*)alloc(KCHEB * 4);
    int*   kmaxp  = (int*)alloc(4);
    int*   ell    = (int*)alloc((size_t)N * 64 * 4);
    unsigned short* xbf   = (unsigned short*)alloc(N64 * 2);
    unsigned short* xu    = (unsigned short*)alloc(UROW * 2);
    unsigned short* hidbf = (unsigned short*)alloc(N64 * 2);
    unsigned short* hidu  = (unsigned short*)alloc(UROW * 2);
    uint4* Wfrag1 = (uint4*)alloc(1024 * 16);
    uint4* Wfrag2 = (uint4*)alloc(512 * 16);
    size_t per_slot = N64 * 2 + UROW * 2 + 512;
    int nslots = (int)((ws_size - off) / per_slot);
    if (nslots > KCHEB - 1) nslots = KCHEB - 1;
    if (nslots < 1) nslots = 1;
    unsigned short* Tarr = (unsigned short*)alloc((size_t)nslots * N64 * 2);
    unsigned short* Uarr = (unsigned short*)alloc((size_t)nslots * UROW * 2);

    hipMemsetAsync(deg, 0, (size_t)N * 4, stream);

    k1_fill_convert_pack<<<FILL_BLOCKS + CONV_BLOCKS + 6, 256, 0, stream>>>(
        row, col, deg, ell, (const float4*)x, (uint4*)xbf,
        Wd, Wh1, Whd, Wh2, Wfrag1, Wfrag2);
    k2_node<<<XU_BLOCKS + PAD_BLOCKS + 2, 256, 0, stream>>>(
        x, deg, dinv, xu, ell, Uarr, hidu, nslots, tp, coeffs, kmaxp);

    const int spmm_grid = N / 16;   // 3125: 16 rows/block (16 lanes/row)
    const int mm_grid = (N + 63) / 64;

    // ---- heat phase 1: base = x ----
    for (int k = 1; k < KCHEB; k++)
        spmm_step<<<spmm_grid, 256, 0, stream>>>(deg, ell, xu, xbf,
                                                 Tarr, Uarr, nslots, dinv, kmaxp, k);
    matmul_hidden<<<mm_grid, 256, 0, stream>>>(xbf, Tarr, nslots, coeffs, kmaxp,
                                               Wfrag1, hidbf, dinv, hidu);

    // ---- heat phase 2: base = hidden ----
    for (int k = 1; k < KCHEB; k++)
        spmm_step<<<spmm_grid, 256, 0, stream>>>(deg, ell, hidu, hidbf,
                                                 Tarr, Uarr, nslots, dinv, kmaxp, k);
    matmul_out<<<mm_grid, 256, 0, stream>>>(hidbf, Tarr, nslots, coeffs, kmaxp,
                                            Wfrag2, (float*)d_out);
}

// Round 12
// 200.901 us; speedup vs baseline: 1.2694x; 1.0981x over previous
//
#include <hip/hip_runtime.h>
#include <math.h>

#define N 50000
#define E 800000
#define KCHEB 10
#define BT 20
#define N64 ((size_t)N * 64)
#define UROW ((size_t)(N + 1) * 64)    // u-arrays have a zeroed pad row N
#define CONV_BLOCKS 1563               // ceil((N64/8)/256)
#define XU_BLOCKS 1563                 // ceil((N64/8 + 8)/256)
#define PAD_BLOCKS 196                 // ceil(N/256)
#define NB 196                         // row buckets (256 rows each)
#define EPB 2048                       // edges per bucket-sort block
#define ABLK ((E + EPB - 1) / EPB)     // 391
#define BCAP 5120                      // bucket capacity (mean 4082, +16 sigma)

typedef __attribute__((ext_vector_type(8))) short short8;   // 8 bf16 = 4 VGPRs
typedef __attribute__((ext_vector_type(4))) float f32x4;    // MFMA acc

// ---- bf16 helpers (manual, RNE) ----
__device__ __forceinline__ unsigned f2bf(float x) {
    unsigned u = __float_as_uint(x);
    return (u + 0x7FFFu + ((u >> 16) & 1u)) >> 16;
}
__device__ __forceinline__ float bf2f(unsigned h) {
    return __uint_as_float(h << 16);
}
__device__ __forceinline__ unsigned packbf(float lo, float hi) {
    return f2bf(lo) | (f2bf(hi) << 16);
}
__device__ __forceinline__ void unpack8(uint4 v, float* f) {
    f[0]=bf2f(v.x&0xFFFFu); f[1]=bf2f(v.x>>16);
    f[2]=bf2f(v.y&0xFFFFu); f[3]=bf2f(v.y>>16);
    f[4]=bf2f(v.z&0xFFFFu); f[5]=bf2f(v.z>>16);
    f[6]=bf2f(v.w&0xFFFFu); f[7]=bf2f(v.w>>16);
}
__device__ __forceinline__ uint4 pack8(const float* f) {
    return make_uint4(packbf(f[0],f[1]),packbf(f[2],f[3]),packbf(f[4],f[5]),packbf(f[6],f[7]));
}

// ---- W pack helper: [Wtop;Wbot] (128 x ncols) -> MFMA B-frags ----
__device__ __forceinline__ void pack_one(const float* Wtop, const float* Wbot,
                                         int ncols, uint4* out, int id) {
    int ntiles = ncols >> 4;
    int lane = id & 63;
    int nt = (id >> 6) % ntiles;
    int kt = id / (64 * ntiles);
    int n = nt * 16 + (lane & 15);
    int k0 = kt * 32 + (lane >> 4) * 8;
    const float* src = (k0 < 64) ? (Wtop + k0 * ncols + n) : (Wbot + (k0 - 64) * ncols + n);
    unsigned r[4];
#pragma unroll
    for (int p = 0; p < 4; p++)
        r[p] = packbf(src[(2 * p) * ncols], src[(2 * p + 1) * ncols]);
    out[id] = make_uint4(r[0], r[1], r[2], r[3]);
}

// ---------------- K1: edge bucket-sort (LDS counting sort) + x->bf16 + W packs --
// Bucket b = row>>8 (256 rows/bucket). Each sort block counting-sorts EPB edges
// in LDS, reserves one contiguous global chunk per bucket (<=NB atomics/block),
// and writes coalesced runs. No global per-row atomics -> no L2 line ping-pong.
// btail pre-zeroed by memset node.
__global__ __launch_bounds__(256) void k1_bucket_conv_pack(
        const int* __restrict__ row, const int* __restrict__ col,
        int* __restrict__ btail, int2* __restrict__ bucketArr,
        const float4* __restrict__ xin, uint4* __restrict__ xbf,
        const float* __restrict__ Wd, const float* __restrict__ Wh1,
        const float* __restrict__ Whd, const float* __restrict__ Wh2,
        uint4* __restrict__ Wfrag1, uint4* __restrict__ Wfrag2) {
    int b = blockIdx.x, tid = threadIdx.x;
    if (b < ABLK) {
        __shared__ int2 buf[EPB];         // 16 KB staging
        __shared__ int cnt[256];
        __shared__ int offs[256];
        __shared__ int gb[256];
        int base = b * EPB;
        int n = E - base; if (n > EPB) n = EPB;
        int r[8], c[8], p[8];
        cnt[tid] = 0;
        __syncthreads();
#pragma unroll
        for (int j = 0; j < 8; j++) {
            int e = base + j * 256 + tid;
            if (e < base + n) {
                r[j] = row[e]; c[j] = col[e];
                p[j] = atomicAdd(&cnt[r[j] >> 8], 1);
            } else r[j] = -1;
        }
        __syncthreads();
        // exclusive scan of cnt -> offs
        offs[tid] = cnt[tid];
        __syncthreads();
        for (int o = 1; o < 256; o <<= 1) {
            int u = (tid >= o) ? offs[tid - o] : 0;
            __syncthreads();
            offs[tid] += u;
            __syncthreads();
        }
        int excl = offs[tid] - cnt[tid];
        __syncthreads();
        offs[tid] = excl;
        // reserve global chunks
        if (tid < NB && cnt[tid] > 0) gb[tid] = atomicAdd(&btail[tid], cnt[tid]);
        __syncthreads();
#pragma unroll
        for (int j = 0; j < 8; j++)
            if (r[j] >= 0) buf[offs[r[j] >> 8] + p[j]] = make_int2(r[j], c[j]);
        __syncthreads();
        for (int i = tid; i < n; i += 256) {
            int2 eg = buf[i];
            int bb = eg.x >> 8;
            int pos = gb[bb] + (i - offs[bb]);
            if (pos < BCAP) bucketArr[(size_t)bb * BCAP + pos] = eg;
        }
    } else if (b < ABLK + CONV_BLOCKS) {
        int i = (b - ABLK) * 256 + tid;
        if (i < (int)(N64 / 8)) {
            float4 a = xin[2 * i], c = xin[2 * i + 1];
            uint4 o;
            o.x = packbf(a.x, a.y); o.y = packbf(a.z, a.w);
            o.z = packbf(c.x, c.y); o.w = packbf(c.z, c.w);
            xbf[i] = o;
        }
    } else if (b < ABLK + CONV_BLOCKS + 4) {
        int id = (b - ABLK - CONV_BLOCKS) * 256 + tid;
        if (id < 1024) pack_one(Wd, Wh1, 64, Wfrag1, id);
    } else {
        int id = (b - ABLK - CONV_BLOCKS - 4) * 256 + tid;
        if (id < 512) pack_one(Whd, Wh2, 32, Wfrag2, id);
    }
}

// ---------------- KB: bucket -> ELL (one block per bucket, LDS row counters) ---
// All per-row slot atomics in LDS; ELL writes span one 64 KB region per block
// (single-XCD L2 locality -> merged writebacks). deg written coalesced.
__global__ __launch_bounds__(256) void k_ell(
        const int2* __restrict__ bucketArr, const int* __restrict__ btail,
        int* __restrict__ ell, int* __restrict__ deg) {
    __shared__ int rcnt[256];
    int b = blockIdx.x, tid = threadIdx.x;
    rcnt[tid] = 0;
    __syncthreads();
    int cnt = btail[b]; if (cnt > BCAP) cnt = BCAP;
    const int2* src = bucketArr + (size_t)b * BCAP;
    for (int i = tid; i < cnt; i += 256) {
        int2 eg = src[i];
        int s = atomicAdd(&rcnt[eg.x & 255], 1);
        if (s < 64) ell[(size_t)eg.x * 64 + s] = eg.y << 7;   // byte offset c*128
    }
    __syncthreads();
    int rr = (b << 8) + tid;
    if (rr < N) deg[rr] = rcnt[tid];
}

// ---------------- K2: dinv + xu + ELL pad + slot pad-row zero + coeffs ---------
// xu = bf16(dinv .* x) with zero row N (gather pad target). ELL rows padded to
// a multiple of 8 with offset N<<7 so spmm's inner unroll is branch-free.
// Coeff cutoff = bf16 ulp (2^-8): terms below the leading term's bf16 rounding
// noise are indistinguishable from quantization already in the pipeline.
__global__ __launch_bounds__(256) void k2_node(
        const float* __restrict__ x, const int* __restrict__ deg,
        float* __restrict__ dinv, unsigned short* __restrict__ xu,
        int* __restrict__ ell, unsigned short* __restrict__ Uarr,
        unsigned short* __restrict__ hidu, int nslots,
        const float* __restrict__ tptr, float* __restrict__ coeffs,
        int* __restrict__ kmaxp) {
    __shared__ float sc[KCHEB];
    int b = blockIdx.x, tid = threadIdx.x;
    if (b < XU_BLOCKS) {
        int i = b * 256 + tid;                 // uint4 index into xu
        if (i < (int)(N64 / 8)) {
            int r = i >> 3, sub = i & 7;
            int d = deg[r];
            float dr = (d > 0) ? rsqrtf((float)d) : 0.f;
            const float* xp = x + (size_t)r * 64 + sub * 8;
            float4 a = *(const float4*)xp, c = *(const float4*)(xp + 4);
            float f[8] = {dr*a.x, dr*a.y, dr*a.z, dr*a.w, dr*c.x, dr*c.y, dr*c.z, dr*c.w};
            ((uint4*)xu)[i] = pack8(f);
            if (sub == 0) dinv[r] = dr;
        } else if (i < (int)(N64 / 8) + 8) {
            ((uint4*)xu)[i] = make_uint4(0, 0, 0, 0);   // row N = 0
        }
    } else if (b < XU_BLOCKS + PAD_BLOCKS) {
        int r = (b - XU_BLOCKS) * 256 + tid;
        if (r < N) {
            int d = deg[r]; if (d > 64) d = 64;
            int dpad = (d + 7) & ~7;
            for (int j = d; j < dpad; j++) ell[(size_t)r * 64 + j] = (N << 7);
        }
    } else if (b == XU_BLOCKS + PAD_BLOCKS) {
        int total = (nslots + 1) * 8;          // nslots u-rows + hidu row, 8 uint4 each
        if (tid < total) {
            int which = tid >> 3, q = tid & 7;
            uint4* dst = (which < nslots)
                ? (uint4*)(Uarr + (size_t)which * UROW + (size_t)N * 64)
                : (uint4*)(hidu + (size_t)N * 64);
            dst[q] = make_uint4(0, 0, 0, 0);
        }
    } else {
        int v = tid;
        if (v < KCHEB) {
            float tt = tptr[0];
            float lt = logf(0.5f * tt);
            float s = 0.f;
            for (int m = 0; m < BT; m++) {
                float lg = lgammaf((float)m + 1.0f) + lgammaf((float)(m + v) + 1.0f);
                s += expf((2.0f * m + (float)v) * lt - lg);
            }
            float c;
            if (v == 0) c = s;
            else c = ((v & 1) == 0) ? 2.0f * s : -2.0f * s;
            coeffs[v] = c;
            sc[v] = c;
        }
        __syncthreads();
        if (v == 0) {
            float c0 = fabsf(sc[0]);
            int kmax = 1;
            for (int k = 1; k < KCHEB; k++)
                if (fabsf(sc[k]) >= 0.00390625f * c0) kmax = k;   // bf16 ulp cutoff
            kmaxp[0] = kmax;
        }
    }
}

// ---------------- SpMM Chebyshev step (ELL, pre-scaled, weight-free) -----------
// 16 lanes/row: two 8-lane half-groups take alternating 8-edge chunks of the
// padded ELL row, combined via shfl_xor(8). Gathers the dinv-pre-scaled u
// vector; applies -dinv[r] in the epilogue (w = dinv[r]*dinv[c] separable).
// Writes T_k (unscaled, for recurrence + heat) and u_k = dinv.*T_k (next gather).
__global__ __launch_bounds__(256) void spmm_step(
        const int* __restrict__ deg, const int* __restrict__ ell,
        const unsigned short* __restrict__ baseu, const unsigned short* __restrict__ baseT,
        unsigned short* __restrict__ Tarr, unsigned short* __restrict__ Uarr,
        int nslots, const float* __restrict__ dinv,
        const int* __restrict__ kmaxp, int k) {
    if (k > 1 && k > kmaxp[0]) return;
    const unsigned short* uin = (k == 1) ? baseu
                              : Uarr + (size_t)((k - 2) % nslots) * UROW;
    const uint4* tkm2 = (const uint4*)((k <= 2) ? baseT
                              : Tarr + (size_t)((k - 3) % nslots) * N64);
    uint4* Tout = (uint4*)(Tarr + (size_t)((k - 1) % nslots) * N64);
    uint4* Uout = (uint4*)(Uarr + (size_t)((k - 1) % nslots) * UROW);
    int tid = threadIdx.x;
    int lane = tid & 63;
    int lane8 = lane & 7;
    int gbase = lane & 56;
    int h = (lane >> 3) & 1;
    int r = blockIdx.x * 16 + (tid >> 6) * 4 + (lane >> 4);
    int d = deg[r]; if (d > 64) d = 64;
    int dpad = (d + 7) & ~7;
    const int* erow = ell + (size_t)r * 64;
    const char* vbase = (const char*)uin;
    int myoff16 = lane8 * 16;
    float a0=0,a1=0,a2=0,a3=0,a4=0,a5=0,a6=0,a7=0;
    for (int j0 = h * 8; j0 < dpad; j0 += 16) {
        int myoff = erow[j0 + lane8];     // pads -> row N (zeros)
#pragma unroll
        for (int i = 0; i < 8; i++) {
            int off = __shfl(myoff, gbase + i, 64);
            uint4 v = *(const uint4*)(vbase + off + myoff16);
            a0 += bf2f(v.x & 0xFFFFu);
            a1 += bf2f(v.x >> 16);
            a2 += bf2f(v.y & 0xFFFFu);
            a3 += bf2f(v.y >> 16);
            a4 += bf2f(v.z & 0xFFFFu);
            a5 += bf2f(v.z >> 16);
            a6 += bf2f(v.w & 0xFFFFu);
            a7 += bf2f(v.w >> 16);
        }
    }
    a0 += __shfl_xor(a0, 8, 64);
    a1 += __shfl_xor(a1, 8, 64);
    a2 += __shfl_xor(a2, 8, 64);
    a3 += __shfl_xor(a3, 8, 64);
    a4 += __shfl_xor(a4, 8, 64);
    a5 += __shfl_xor(a5, 8, 64);
    a6 += __shfl_xor(a6, 8, 64);
    a7 += __shfl_xor(a7, 8, 64);
    if (h == 0) {
        float dr = dinv[r];
        float ndr = -dr;
        float s0=ndr*a0, s1=ndr*a1, s2=ndr*a2, s3=ndr*a3;
        float s4=ndr*a4, s5=ndr*a5, s6=ndr*a6, s7=ndr*a7;
        int idx = r * 8 + lane8;
        if (k >= 2) {
            uint4 tm = tkm2[idx];
            s0 = 2.f*s0 - bf2f(tm.x & 0xFFFFu);
            s1 = 2.f*s1 - bf2f(tm.x >> 16);
            s2 = 2.f*s2 - bf2f(tm.y & 0xFFFFu);
            s3 = 2.f*s3 - bf2f(tm.y >> 16);
            s4 = 2.f*s4 - bf2f(tm.z & 0xFFFFu);
            s5 = 2.f*s5 - bf2f(tm.z >> 16);
            s6 = 2.f*s6 - bf2f(tm.w & 0xFFFFu);
            s7 = 2.f*s7 - bf2f(tm.w >> 16);
        }
        float t8[8] = {s0,s1,s2,s3,s4,s5,s6,s7};
        Tout[idx] = pack8(t8);
        float u8[8] = {dr*s0,dr*s1,dr*s2,dr*s3,dr*s4,dr*s5,dr*s6,dr*s7};
        Uout[idx] = pack8(u8);
    }
}

// ---------------- MFMA matmul: hidden = relu([base|heat] @ Bfrag), 64 cols ------
// Also emits hidu = bf16(dinv .* hidden) as phase-2's pre-scaled gather source.
__global__ __launch_bounds__(256) void matmul_hidden(
        const unsigned short* __restrict__ basebf, const unsigned short* __restrict__ Tarr,
        int nslots, const float* __restrict__ coeffs, const int* __restrict__ kmaxp,
        const uint4* __restrict__ Wfrag, unsigned short* __restrict__ hidbf,
        const float* __restrict__ dinv, unsigned short* __restrict__ hidu) {
    __shared__ __align__(16) unsigned short At[64][136];   // pad 8 -> row stride 272B
    int tid = threadIdx.x;
    int row0 = blockIdx.x * 64;
    int kmax = kmaxp[0]; if (kmax > KCHEB - 1) kmax = KCHEB - 1;
    float c0 = coeffs[0];
    for (int u = tid; u < 1024; u += 256) {
        int rr = u >> 4, seg = u & 15;
        int r = row0 + rr;
        uint4 val = make_uint4(0, 0, 0, 0);
        int col;
        if (seg < 8) {
            col = seg * 8;
            if (r < N) val = *(const uint4*)(basebf + (size_t)r * 64 + seg * 8);
        } else {
            int s = seg - 8;
            col = 64 + s * 8;
            if (r < N) {
                uint4 xv = *(const uint4*)(basebf + (size_t)r * 64 + s * 8);
                float h[8], f[8];
                unpack8(xv, f);
#pragma unroll
                for (int q = 0; q < 8; q++) h[q] = c0 * f[q];
                for (int j = 1; j <= kmax; j++) {
                    const unsigned short* Tj = Tarr + (size_t)((j - 1) % nslots) * N64;
                    uint4 tv = *(const uint4*)(Tj + (size_t)r * 64 + s * 8);
                    float g[8];
                    unpack8(tv, g);
                    float cj = coeffs[j];
#pragma unroll
                    for (int q = 0; q < 8; q++) h[q] = fmaf(cj, g[q], h[q]);
                }
                val = pack8(h);
            }
        }
        *(uint4*)&At[rr][col] = val;
    }
    __syncthreads();
    int wv = tid >> 6, lane = tid & 63;
    int m0 = wv * 16;
    short8 afr[4];
#pragma unroll
    for (int kt = 0; kt < 4; kt++)
        afr[kt] = *(const short8*)&At[m0 + (lane & 15)][kt * 32 + (lane >> 4) * 8];
    f32x4 acc[4];
#pragma unroll
    for (int nt = 0; nt < 4; nt++) acc[nt] = (f32x4){0.f, 0.f, 0.f, 0.f};
#pragma unroll
    for (int nt = 0; nt < 4; nt++) {
#pragma unroll
        for (int kt = 0; kt < 4; kt++) {
            short8 bfr = *(const short8*)&Wfrag[kt * 256 + nt * 64 + lane];
            acc[nt] = __builtin_amdgcn_mfma_f32_16x16x32_bf16(afr[kt], bfr, acc[nt], 0, 0, 0);
        }
    }
    float drow[4];
#pragma unroll
    for (int i = 0; i < 4; i++) {
        int r = row0 + m0 + (lane >> 4) * 4 + i;
        drow[i] = (r < N) ? dinv[r] : 0.f;
    }
#pragma unroll
    for (int nt = 0; nt < 4; nt++) {
#pragma unroll
        for (int i = 0; i < 4; i++) {
            int r = row0 + m0 + (lane >> 4) * 4 + i;
            if (r < N) {
                float hv = fmaxf(acc[nt][i], 0.f);
                size_t o = (size_t)r * 64 + nt * 16 + (lane & 15);
                hidbf[o] = (unsigned short)f2bf(hv);
                hidu[o]  = (unsigned short)f2bf(drow[i] * hv);
            }
        }
    }
}

// ---------------- MFMA matmul + log_softmax: out = lsm([hid|heat2] @ Bfrag) ----
__global__ __launch_bounds__(256) void matmul_out(
        const unsigned short* __restrict__ basebf, const unsigned short* __restrict__ Tarr,
        int nslots, const float* __restrict__ coeffs, const int* __restrict__ kmaxp,
        const uint4* __restrict__ Wfrag, float* __restrict__ out) {
    __shared__ __align__(16) unsigned short At[64][136];
    int tid = threadIdx.x;
    int row0 = blockIdx.x * 64;
    int kmax = kmaxp[0]; if (kmax > KCHEB - 1) kmax = KCHEB - 1;
    float c0 = coeffs[0];
    for (int u = tid; u < 1024; u += 256) {
        int rr = u >> 4, seg = u & 15;
        int r = row0 + rr;
        uint4 val = make_uint4(0, 0, 0, 0);
        int col;
        if (seg < 8) {
            col = seg * 8;
            if (r < N) val = *(const uint4*)(basebf + (size_t)r * 64 + seg * 8);
        } else {
            int s = seg - 8;
            col = 64 + s * 8;
            if (r < N) {
                uint4 xv = *(const uint4*)(basebf + (size_t)r * 64 + s * 8);
                float h[8], f[8];
                unpack8(xv, f);
#pragma unroll
                for (int q = 0; q < 8; q++) h[q] = c0 * f[q];
                for (int j = 1; j <= kmax; j++) {
                    const unsigned short* Tj = Tarr + (size_t)((j - 1) % nslots) * N64;
                    uint4 tv = *(const uint4*)(Tj + (size_t)r * 64 + s * 8);
                    float g[8];
                    unpack8(tv, g);
                    float cj = coeffs[j];
#pragma unroll
                    for (int q = 0; q < 8; q++) h[q] = fmaf(cj, g[q], h[q]);
                }
                val = pack8(h);
            }
        }
        *(uint4*)&At[rr][col] = val;
    }
    __syncthreads();
    int wv = tid >> 6, lane = tid & 63;
    int m0 = wv * 16;
    short8 afr[4];
#pragma unroll
    for (int kt = 0; kt < 4; kt++)
        afr[kt] = *(const short8*)&At[m0 + (lane & 15)][kt * 32 + (lane >> 4) * 8];
    f32x4 acc[2];
    acc[0] = (f32x4){0.f, 0.f, 0.f, 0.f};
    acc[1] = (f32x4){0.f, 0.f, 0.f, 0.f};
#pragma unroll
    for (int nt = 0; nt < 2; nt++) {
#pragma unroll
        for (int kt = 0; kt < 4; kt++) {
            short8 bfr = *(const short8*)&Wfrag[kt * 128 + nt * 64 + lane];
            acc[nt] = __builtin_amdgcn_mfma_f32_16x16x32_bf16(afr[kt], bfr, acc[nt], 0, 0, 0);
        }
    }
#pragma unroll
    for (int i = 0; i < 4; i++) {
        float f0 = acc[0][i], f1 = acc[1][i];
        float m = fmaxf(f0, f1);
#pragma unroll
        for (int o = 1; o < 16; o <<= 1) m = fmaxf(m, __shfl_xor(m, o, 64));
        float s = expf(f0 - m) + expf(f1 - m);
#pragma unroll
        for (int o = 1; o < 16; o <<= 1) s += __shfl_xor(s, o, 64);
        float ls = m + logf(s);
        int r = row0 + m0 + (lane >> 4) * 4 + i;
        if (r < N) {
            out[(size_t)r * 32 + (lane & 15)] = f0 - ls;
            out[(size_t)r * 32 + 16 + (lane & 15)] = f1 - ls;
        }
    }
}

extern "C" void kernel_launch(void* const* d_in, const int* in_sizes, int n_in,
                              void* d_out, int out_size, void* d_ws, size_t ws_size,
                              hipStream_t stream) {
    const float* x   = (const float*)d_in[0];
    const int*   ei  = (const int*)d_in[1];
    const float* Wd  = (const float*)d_in[2];
    const float* Wh1 = (const float*)d_in[3];
    const float* Whd = (const float*)d_in[4];
    const float* Wh2 = (const float*)d_in[5];
    const float* tp  = (const float*)d_in[6];
    const int* row = ei;
    const int* col = ei + E;

    size_t off = 0;
    auto alloc = [&](size_t bytes) -> void* {
        void* p = (char*)d_ws + off;
        off += (bytes + 255) & ~(size_t)255;
        return p;
    };
    int*   btail  = (int*)alloc((size_t)256 * 4);          // bucket tails (zeroed)
    int*   deg    = (int*)alloc((size_t)N * 4);
    float* dinv   = (float*)alloc((size_t)N * 4);
    float* coeffs = (float*)alloc(KCHEB * 4);
    int*   kmaxp  = (int*)alloc(4);
    int*   ell    = (int*)alloc((size_t)N * 64 * 4);
    int2*  bucketArr = (int2*)alloc((size_t)NB * BCAP * 8);   // 8.0 MB
    unsigned short* xbf   = (unsigned short*)alloc(N64 * 2);
    unsigned short* xu    = (unsigned short*)alloc(UROW * 2);
    unsigned short* hidbf = (unsigned short*)alloc(N64 * 2);
    unsigned short* hidu  = (unsigned short*)alloc(UROW * 2);
    uint4* Wfrag1 = (uint4*)alloc(1024 * 16);
    uint4* Wfrag2 = (uint4*)alloc(512 * 16);
    size_t per_slot = N64 * 2 + UROW * 2 + 512;
    int nslots = (int)((ws_size - off) / per_slot);
    if (nslots > KCHEB - 1) nslots = KCHEB - 1;
    if (nslots < 1) nslots = 1;
    unsigned short* Tarr = (unsigned short*)alloc((size_t)nslots * N64 * 2);
    unsigned short* Uarr = (unsigned short*)alloc((size_t)nslots * UROW * 2);

    hipMemsetAsync(btail, 0, (size_t)256 * 4, stream);

    k1_bucket_conv_pack<<<ABLK + CONV_BLOCKS + 6, 256, 0, stream>>>(
        row, col, btail, bucketArr, (const float4*)x, (uint4*)xbf,
        Wd, Wh1, Whd, Wh2, Wfrag1, Wfrag2);
    k_ell<<<NB, 256, 0, stream>>>(bucketArr, btail, ell, deg);
    k2_node<<<XU_BLOCKS + PAD_BLOCKS + 2, 256, 0, stream>>>(
        x, deg, dinv, xu, ell, Uarr, hidu, nslots, tp, coeffs, kmaxp);

    const int spmm_grid = N / 16;   // 3125: 16 rows/block (16 lanes/row)
    const int mm_grid = (N + 63) / 64;

    // ---- heat phase 1: base = x ----
    for (int k = 1; k < KCHEB; k++)
        spmm_step<<<spmm_grid, 256, 0, stream>>>(deg, ell, xu, xbf,
                                                 Tarr, Uarr, nslots, dinv, kmaxp, k);
    matmul_hidden<<<mm_grid, 256, 0, stream>>>(xbf, Tarr, nslots, coeffs, kmaxp,
                                               Wfrag1, hidbf, dinv, hidu);

    // ---- heat phase 2: base = hidden ----
    for (int k = 1; k < KCHEB; k++)
        spmm_step<<<spmm_grid, 256, 0, stream>>>(deg, ell, hidu, hidbf,
                                                 Tarr, Uarr, nslots, dinv, kmaxp, k);
    matmul_out<<<mm_grid, 256, 0, stream>>>(hidbf, Tarr, nslots, coeffs, kmaxp,
                                            Wfrag2, (float*)d_out);
}

// Round 13
// 171.609 us; speedup vs baseline: 1.4861x; 1.1707x over previous
//
#include <hip/hip_runtime.h>
#include <math.h>

#define N 50000
#define E 800000
#define KCHEB 10
#define BT 20
#define N64 ((size_t)N * 64)
#define UROW ((size_t)(N + 1) * 64)    // u-arrays have a zeroed pad row N
#define CONV_BLOCKS 1563               // ceil((N64/8)/256)
#define XU_BLOCKS 1563                 // ceil((N64/8 + 8)/256)
#define PAD_BLOCKS 196                 // ceil(N/256)
#define NB 196                         // row buckets (256 rows each)
#define EPB 2048                       // edges per bucket-sort block
#define ABLK ((E + EPB - 1) / EPB)     // 391
#define BCAP 5120                      // bucket capacity (mean 4082, +16 sigma)
#define PHASE_GRID 1024                // 4 blocks/CU co-resident (launch_bounds)
#define NGROUP 3125                    // N/16 row-groups

typedef __attribute__((ext_vector_type(8))) short short8;   // 8 bf16 = 4 VGPRs
typedef __attribute__((ext_vector_type(4))) float f32x4;    // MFMA acc

// ---- bf16 helpers (manual, RNE) ----
__device__ __forceinline__ unsigned f2bf(float x) {
    unsigned u = __float_as_uint(x);
    return (u + 0x7FFFu + ((u >> 16) & 1u)) >> 16;
}
__device__ __forceinline__ float bf2f(unsigned h) {
    return __uint_as_float(h << 16);
}
__device__ __forceinline__ unsigned packbf(float lo, float hi) {
    return f2bf(lo) | (f2bf(hi) << 16);
}
__device__ __forceinline__ void unpack8(uint4 v, float* f) {
    f[0]=bf2f(v.x&0xFFFFu); f[1]=bf2f(v.x>>16);
    f[2]=bf2f(v.y&0xFFFFu); f[3]=bf2f(v.y>>16);
    f[4]=bf2f(v.z&0xFFFFu); f[5]=bf2f(v.z>>16);
    f[6]=bf2f(v.w&0xFFFFu); f[7]=bf2f(v.w>>16);
}
__device__ __forceinline__ uint4 pack8(const float* f) {
    return make_uint4(packbf(f[0],f[1]),packbf(f[2],f[3]),packbf(f[4],f[5]),packbf(f[6],f[7]));
}

// ---- W pack helper: [Wtop;Wbot] (128 x ncols) -> MFMA B-frags ----
__device__ __forceinline__ void pack_one(const float* Wtop, const float* Wbot,
                                         int ncols, uint4* out, int id) {
    int ntiles = ncols >> 4;
    int lane = id & 63;
    int nt = (id >> 6) % ntiles;
    int kt = id / (64 * ntiles);
    int n = nt * 16 + (lane & 15);
    int k0 = kt * 32 + (lane >> 4) * 8;
    const float* src = (k0 < 64) ? (Wtop + k0 * ncols + n) : (Wbot + (k0 - 64) * ncols + n);
    unsigned r[4];
#pragma unroll
    for (int p = 0; p < 4; p++)
        r[p] = packbf(src[(2 * p) * ncols], src[(2 * p + 1) * ncols]);
    out[id] = make_uint4(r[0], r[1], r[2], r[3]);
}

// ---------------- K1: edge bucket-sort (LDS counting sort) + x->bf16 + W packs --
__global__ __launch_bounds__(256) void k1_bucket_conv_pack(
        const int* __restrict__ row, const int* __restrict__ col,
        int* __restrict__ btail, int2* __restrict__ bucketArr,
        const float4* __restrict__ xin, uint4* __restrict__ xbf,
        const float* __restrict__ Wd, const float* __restrict__ Wh1,
        const float* __restrict__ Whd, const float* __restrict__ Wh2,
        uint4* __restrict__ Wfrag1, uint4* __restrict__ Wfrag2) {
    int b = blockIdx.x, tid = threadIdx.x;
    if (b < ABLK) {
        __shared__ int2 buf[EPB];         // 16 KB staging
        __shared__ int cnt[256];
        __shared__ int offs[256];
        __shared__ int gb[256];
        int base = b * EPB;
        int n = E - base; if (n > EPB) n = EPB;
        int r[8], c[8], p[8];
        cnt[tid] = 0;
        __syncthreads();
#pragma unroll
        for (int j = 0; j < 8; j++) {
            int e = base + j * 256 + tid;
            if (e < base + n) {
                r[j] = row[e]; c[j] = col[e];
                p[j] = atomicAdd(&cnt[r[j] >> 8], 1);
            } else r[j] = -1;
        }
        __syncthreads();
        offs[tid] = cnt[tid];
        __syncthreads();
        for (int o = 1; o < 256; o <<= 1) {
            int u = (tid >= o) ? offs[tid - o] : 0;
            __syncthreads();
            offs[tid] += u;
            __syncthreads();
        }
        int excl = offs[tid] - cnt[tid];
        __syncthreads();
        offs[tid] = excl;
        if (tid < NB && cnt[tid] > 0) gb[tid] = atomicAdd(&btail[tid], cnt[tid]);
        __syncthreads();
#pragma unroll
        for (int j = 0; j < 8; j++)
            if (r[j] >= 0) buf[offs[r[j] >> 8] + p[j]] = make_int2(r[j], c[j]);
        __syncthreads();
        for (int i = tid; i < n; i += 256) {
            int2 eg = buf[i];
            int bb = eg.x >> 8;
            int pos = gb[bb] + (i - offs[bb]);
            if (pos < BCAP) bucketArr[(size_t)bb * BCAP + pos] = eg;
        }
    } else if (b < ABLK + CONV_BLOCKS) {
        int i = (b - ABLK) * 256 + tid;
        if (i < (int)(N64 / 8)) {
            float4 a = xin[2 * i], c = xin[2 * i + 1];
            uint4 o;
            o.x = packbf(a.x, a.y); o.y = packbf(a.z, a.w);
            o.z = packbf(c.x, c.y); o.w = packbf(c.z, c.w);
            xbf[i] = o;
        }
    } else if (b < ABLK + CONV_BLOCKS + 4) {
        int id = (b - ABLK - CONV_BLOCKS) * 256 + tid;
        if (id < 1024) pack_one(Wd, Wh1, 64, Wfrag1, id);
    } else {
        int id = (b - ABLK - CONV_BLOCKS - 4) * 256 + tid;
        if (id < 512) pack_one(Whd, Wh2, 32, Wfrag2, id);
    }
}

// ---------------- KB: bucket -> ELL (one block per bucket, LDS row counters) ---
__global__ __launch_bounds__(256) void k_ell(
        const int2* __restrict__ bucketArr, const int* __restrict__ btail,
        int* __restrict__ ell, int* __restrict__ deg) {
    __shared__ int rcnt[256];
    int b = blockIdx.x, tid = threadIdx.x;
    rcnt[tid] = 0;
    __syncthreads();
    int cnt = btail[b]; if (cnt > BCAP) cnt = BCAP;
    const int2* src = bucketArr + (size_t)b * BCAP;
    for (int i = tid; i < cnt; i += 256) {
        int2 eg = src[i];
        int s = atomicAdd(&rcnt[eg.x & 255], 1);
        if (s < 64) ell[(size_t)eg.x * 64 + s] = eg.y << 7;   // byte offset c*128
    }
    __syncthreads();
    int rr = (b << 8) + tid;
    if (rr < N) deg[rr] = rcnt[tid];
}

// ---------------- K2: dinv + xu + ELL pad + slot pad-row zero + coeffs ---------
__global__ __launch_bounds__(256) void k2_node(
        const float* __restrict__ x, const int* __restrict__ deg,
        float* __restrict__ dinv, unsigned short* __restrict__ xu,
        int* __restrict__ ell, unsigned short* __restrict__ Uarr,
        unsigned short* __restrict__ hidu, int nslots,
        const float* __restrict__ tptr, float* __restrict__ coeffs,
        int* __restrict__ kmaxp) {
    __shared__ float sc[KCHEB];
    int b = blockIdx.x, tid = threadIdx.x;
    if (b < XU_BLOCKS) {
        int i = b * 256 + tid;                 // uint4 index into xu
        if (i < (int)(N64 / 8)) {
            int r = i >> 3, sub = i & 7;
            int d = deg[r];
            float dr = (d > 0) ? rsqrtf((float)d) : 0.f;
            const float* xp = x + (size_t)r * 64 + sub * 8;
            float4 a = *(const float4*)xp, c = *(const float4*)(xp + 4);
            float f[8] = {dr*a.x, dr*a.y, dr*a.z, dr*a.w, dr*c.x, dr*c.y, dr*c.z, dr*c.w};
            ((uint4*)xu)[i] = pack8(f);
            if (sub == 0) dinv[r] = dr;
        } else if (i < (int)(N64 / 8) + 8) {
            ((uint4*)xu)[i] = make_uint4(0, 0, 0, 0);   // row N = 0
        }
    } else if (b < XU_BLOCKS + PAD_BLOCKS) {
        int r = (b - XU_BLOCKS) * 256 + tid;
        if (r < N) {
            int d = deg[r]; if (d > 64) d = 64;
            int dpad = (d + 7) & ~7;
            for (int j = d; j < dpad; j++) ell[(size_t)r * 64 + j] = (N << 7);
        }
    } else if (b == XU_BLOCKS + PAD_BLOCKS) {
        int total = (nslots + 1) * 8;          // nslots u-rows + hidu row, 8 uint4 each
        if (tid < total) {
            int which = tid >> 3, q = tid & 7;
            uint4* dst = (which < nslots)
                ? (uint4*)(Uarr + (size_t)which * UROW + (size_t)N * 64)
                : (uint4*)(hidu + (size_t)N * 64);
            dst[q] = make_uint4(0, 0, 0, 0);
        }
    } else {
        int v = tid;
        if (v < KCHEB) {
            float tt = tptr[0];
            float lt = logf(0.5f * tt);
            float s = 0.f;
            for (int m = 0; m < BT; m++) {
                float lg = lgammaf((float)m + 1.0f) + lgammaf((float)(m + v) + 1.0f);
                s += expf((2.0f * m + (float)v) * lt - lg);
            }
            float c;
            if (v == 0) c = s;
            else c = ((v & 1) == 0) ? 2.0f * s : -2.0f * s;
            coeffs[v] = c;
            sc[v] = c;
        }
        __syncthreads();
        if (v == 0) {
            float c0 = fabsf(sc[0]);
            int kmax = 1;
            for (int k = 1; k < KCHEB; k++)
                if (fabsf(sc[k]) >= 0.00390625f * c0) kmax = k;   // bf16 ulp cutoff
            kmaxp[0] = kmax;
        }
    }
}

// ---------------- persistent SpMM phase: loops k=1..kmax, NORMAL launch --------
// R8 ran this shape under hipLaunchCooperativeKernel and gathers went 15x slow
// with ZERO grid.sync in the hot path (kmax=1) -> the coop launch MODE was the
// problem, not the persistent shape. Here: normal launch, 1024 blocks with
// __launch_bounds__(256,4) (4 blocks/CU co-resident by capacity), grid-stride
// over 3125 row-groups, and a generation-counter spin barrier (agent-scope
// acquire/release) between consecutive LIVE steps only. At kmax==1 the barrier
// path never executes (no deadlock exposure; bf16-ulp cutoff gives kmax=1 for
// small t). Slot aliasing across a barrier needs nslots>=3 (checked host-side).
__global__ __launch_bounds__(256, 4) void spmm_phase(
        const int* __restrict__ deg, const int* __restrict__ ell,
        const unsigned short* __restrict__ baseu, const unsigned short* __restrict__ baseT,
        unsigned short* __restrict__ Tarr, unsigned short* __restrict__ Uarr,
        int nslots, const float* __restrict__ dinv,
        const int* __restrict__ kmaxp, int* __restrict__ barcnt) {
    int tid = threadIdx.x;
    int lane = tid & 63;
    int lane8 = lane & 7;
    int gbase = lane & 56;
    int h = (lane >> 3) & 1;
    int myoff16 = lane8 * 16;
    int kmax = kmaxp[0]; if (kmax > KCHEB - 1) kmax = KCHEB - 1;
    for (int k = 1; k <= kmax; k++) {
        const unsigned short* uin = (k == 1) ? baseu
                                  : Uarr + (size_t)((k - 2) % nslots) * UROW;
        const uint4* tkm2 = (const uint4*)((k <= 2) ? baseT
                                  : Tarr + (size_t)((k - 3) % nslots) * N64);
        uint4* Tout = (uint4*)(Tarr + (size_t)((k - 1) % nslots) * N64);
        uint4* Uout = (uint4*)(Uarr + (size_t)((k - 1) % nslots) * UROW);
        const char* vbase = (const char*)uin;
        for (int rb = blockIdx.x; rb < NGROUP; rb += PHASE_GRID) {
            int r = rb * 16 + (tid >> 6) * 4 + (lane >> 4);
            int d = deg[r]; if (d > 64) d = 64;
            int dpad = (d + 7) & ~7;
            const int* erow = ell + (size_t)r * 64;
            float a0=0,a1=0,a2=0,a3=0,a4=0,a5=0,a6=0,a7=0;
            for (int j0 = h * 8; j0 < dpad; j0 += 16) {
                int myoff = erow[j0 + lane8];     // pads -> row N (zeros)
#pragma unroll
                for (int i = 0; i < 8; i++) {
                    int off = __shfl(myoff, gbase + i, 64);
                    uint4 v = *(const uint4*)(vbase + off + myoff16);
                    a0 += bf2f(v.x & 0xFFFFu);
                    a1 += bf2f(v.x >> 16);
                    a2 += bf2f(v.y & 0xFFFFu);
                    a3 += bf2f(v.y >> 16);
                    a4 += bf2f(v.z & 0xFFFFu);
                    a5 += bf2f(v.z >> 16);
                    a6 += bf2f(v.w & 0xFFFFu);
                    a7 += bf2f(v.w >> 16);
                }
            }
            a0 += __shfl_xor(a0, 8, 64);
            a1 += __shfl_xor(a1, 8, 64);
            a2 += __shfl_xor(a2, 8, 64);
            a3 += __shfl_xor(a3, 8, 64);
            a4 += __shfl_xor(a4, 8, 64);
            a5 += __shfl_xor(a5, 8, 64);
            a6 += __shfl_xor(a6, 8, 64);
            a7 += __shfl_xor(a7, 8, 64);
            if (h == 0) {
                float dr = dinv[r];
                float ndr = -dr;
                float s0=ndr*a0, s1=ndr*a1, s2=ndr*a2, s3=ndr*a3;
                float s4=ndr*a4, s5=ndr*a5, s6=ndr*a6, s7=ndr*a7;
                int idx = r * 8 + lane8;
                if (k >= 2) {
                    uint4 tm = tkm2[idx];
                    s0 = 2.f*s0 - bf2f(tm.x & 0xFFFFu);
                    s1 = 2.f*s1 - bf2f(tm.x >> 16);
                    s2 = 2.f*s2 - bf2f(tm.y & 0xFFFFu);
                    s3 = 2.f*s3 - bf2f(tm.y >> 16);
                    s4 = 2.f*s4 - bf2f(tm.z & 0xFFFFu);
                    s5 = 2.f*s5 - bf2f(tm.z >> 16);
                    s6 = 2.f*s6 - bf2f(tm.w & 0xFFFFu);
                    s7 = 2.f*s7 - bf2f(tm.w >> 16);
                }
                float t8[8] = {s0,s1,s2,s3,s4,s5,s6,s7};
                Tout[idx] = pack8(t8);
                float u8[8] = {dr*s0,dr*s1,dr*s2,dr*s3,dr*s4,dr*s5,dr*s6,dr*s7};
                Uout[idx] = pack8(u8);
            }
        }
        if (k < kmax) {
            // inter-step device barrier (generation = k, monotone counter)
            __threadfence();
            __syncthreads();
            if (tid == 0) {
                __hip_atomic_fetch_add(barcnt, 1, __ATOMIC_ACQ_REL, __HIP_MEMORY_SCOPE_AGENT);
                int target = PHASE_GRID * k;
                while (__hip_atomic_load(barcnt, __ATOMIC_ACQUIRE, __HIP_MEMORY_SCOPE_AGENT) < target)
                    __builtin_amdgcn_s_sleep(8);
            }
            __syncthreads();
        }
    }
}

// ---------------- MFMA matmul: hidden = relu([base|heat] @ Bfrag), 64 cols ------
// Also emits hidu = bf16(dinv .* hidden) as phase-2's pre-scaled gather source.
__global__ __launch_bounds__(256) void matmul_hidden(
        const unsigned short* __restrict__ basebf, const unsigned short* __restrict__ Tarr,
        int nslots, const float* __restrict__ coeffs, const int* __restrict__ kmaxp,
        const uint4* __restrict__ Wfrag, unsigned short* __restrict__ hidbf,
        const float* __restrict__ dinv, unsigned short* __restrict__ hidu) {
    __shared__ __align__(16) unsigned short At[64][136];   // pad 8 -> row stride 272B
    int tid = threadIdx.x;
    int row0 = blockIdx.x * 64;
    int kmax = kmaxp[0]; if (kmax > KCHEB - 1) kmax = KCHEB - 1;
    float c0 = coeffs[0];
    for (int u = tid; u < 1024; u += 256) {
        int rr = u >> 4, seg = u & 15;
        int r = row0 + rr;
        uint4 val = make_uint4(0, 0, 0, 0);
        int col;
        if (seg < 8) {
            col = seg * 8;
            if (r < N) val = *(const uint4*)(basebf + (size_t)r * 64 + seg * 8);
        } else {
            int s = seg - 8;
            col = 64 + s * 8;
            if (r < N) {
                uint4 xv = *(const uint4*)(basebf + (size_t)r * 64 + s * 8);
                float h[8], f[8];
                unpack8(xv, f);
#pragma unroll
                for (int q = 0; q < 8; q++) h[q] = c0 * f[q];
                for (int j = 1; j <= kmax; j++) {
                    const unsigned short* Tj = Tarr + (size_t)((j - 1) % nslots) * N64;
                    uint4 tv = *(const uint4*)(Tj + (size_t)r * 64 + s * 8);
                    float g[8];
                    unpack8(tv, g);
                    float cj = coeffs[j];
#pragma unroll
                    for (int q = 0; q < 8; q++) h[q] = fmaf(cj, g[q], h[q]);
                }
                val = pack8(h);
            }
        }
        *(uint4*)&At[rr][col] = val;
    }
    __syncthreads();
    int wv = tid >> 6, lane = tid & 63;
    int m0 = wv * 16;
    short8 afr[4];
#pragma unroll
    for (int kt = 0; kt < 4; kt++)
        afr[kt] = *(const short8*)&At[m0 + (lane & 15)][kt * 32 + (lane >> 4) * 8];
    f32x4 acc[4];
#pragma unroll
    for (int nt = 0; nt < 4; nt++) acc[nt] = (f32x4){0.f, 0.f, 0.f, 0.f};
#pragma unroll
    for (int nt = 0; nt < 4; nt++) {
#pragma unroll
        for (int kt = 0; kt < 4; kt++) {
            short8 bfr = *(const short8*)&Wfrag[kt * 256 + nt * 64 + lane];
            acc[nt] = __builtin_amdgcn_mfma_f32_16x16x32_bf16(afr[kt], bfr, acc[nt], 0, 0, 0);
        }
    }
    float drow[4];
#pragma unroll
    for (int i = 0; i < 4; i++) {
        int r = row0 + m0 + (lane >> 4) * 4 + i;
        drow[i] = (r < N) ? dinv[r] : 0.f;
    }
#pragma unroll
    for (int nt = 0; nt < 4; nt++) {
#pragma unroll
        for (int i = 0; i < 4; i++) {
            int r = row0 + m0 + (lane >> 4) * 4 + i;
            if (r < N) {
                float hv = fmaxf(acc[nt][i], 0.f);
                size_t o = (size_t)r * 64 + nt * 16 + (lane & 15);
                hidbf[o] = (unsigned short)f2bf(hv);
                hidu[o]  = (unsigned short)f2bf(drow[i] * hv);
            }
        }
    }
}

// ---------------- MFMA matmul + log_softmax: out = lsm([hid|heat2] @ Bfrag) ----
__global__ __launch_bounds__(256) void matmul_out(
        const unsigned short* __restrict__ basebf, const unsigned short* __restrict__ Tarr,
        int nslots, const float* __restrict__ coeffs, const int* __restrict__ kmaxp,
        const uint4* __restrict__ Wfrag, float* __restrict__ out) {
    __shared__ __align__(16) unsigned short At[64][136];
    int tid = threadIdx.x;
    int row0 = blockIdx.x * 64;
    int kmax = kmaxp[0]; if (kmax > KCHEB - 1) kmax = KCHEB - 1;
    float c0 = coeffs[0];
    for (int u = tid; u < 1024; u += 256) {
        int rr = u >> 4, seg = u & 15;
        int r = row0 + rr;
        uint4 val = make_uint4(0, 0, 0, 0);
        int col;
        if (seg < 8) {
            col = seg * 8;
            if (r < N) val = *(const uint4*)(basebf + (size_t)r * 64 + seg * 8);
        } else {
            int s = seg - 8;
            col = 64 + s * 8;
            if (r < N) {
                uint4 xv = *(const uint4*)(basebf + (size_t)r * 64 + s * 8);
                float h[8], f[8];
                unpack8(xv, f);
#pragma unroll
                for (int q = 0; q < 8; q++) h[q] = c0 * f[q];
                for (int j = 1; j <= kmax; j++) {
                    const unsigned short* Tj = Tarr + (size_t)((j - 1) % nslots) * N64;
                    uint4 tv = *(const uint4*)(Tj + (size_t)r * 64 + s * 8);
                    float g[8];
                    unpack8(tv, g);
                    float cj = coeffs[j];
#pragma unroll
                    for (int q = 0; q < 8; q++) h[q] = fmaf(cj, g[q], h[q]);
                }
                val = pack8(h);
            }
        }
        *(uint4*)&At[rr][col] = val;
    }
    __syncthreads();
    int wv = tid >> 6, lane = tid & 63;
    int m0 = wv * 16;
    short8 afr[4];
#pragma unroll
    for (int kt = 0; kt < 4; kt++)
        afr[kt] = *(const short8*)&At[m0 + (lane & 15)][kt * 32 + (lane >> 4) * 8];
    f32x4 acc[2];
    acc[0] = (f32x4){0.f, 0.f, 0.f, 0.f};
    acc[1] = (f32x4){0.f, 0.f, 0.f, 0.f};
#pragma unroll
    for (int nt = 0; nt < 2; nt++) {
#pragma unroll
        for (int kt = 0; kt < 4; kt++) {
            short8 bfr = *(const short8*)&Wfrag[kt * 128 + nt * 64 + lane];
            acc[nt] = __builtin_amdgcn_mfma_f32_16x16x32_bf16(afr[kt], bfr, acc[nt], 0, 0, 0);
        }
    }
#pragma unroll
    for (int i = 0; i < 4; i++) {
        float f0 = acc[0][i], f1 = acc[1][i];
        float m = fmaxf(f0, f1);
#pragma unroll
        for (int o = 1; o < 16; o <<= 1) m = fmaxf(m, __shfl_xor(m, o, 64));
        float s = expf(f0 - m) + expf(f1 - m);
#pragma unroll
        for (int o = 1; o < 16; o <<= 1) s += __shfl_xor(s, o, 64);
        float ls = m + logf(s);
        int r = row0 + m0 + (lane >> 4) * 4 + i;
        if (r < N) {
            out[(size_t)r * 32 + (lane & 15)] = f0 - ls;
            out[(size_t)r * 32 + 16 + (lane & 15)] = f1 - ls;
        }
    }
}

extern "C" void kernel_launch(void* const* d_in, const int* in_sizes, int n_in,
                              void* d_out, int out_size, void* d_ws, size_t ws_size,
                              hipStream_t stream) {
    const float* x   = (const float*)d_in[0];
    const int*   ei  = (const int*)d_in[1];
    const float* Wd  = (const float*)d_in[2];
    const float* Wh1 = (const float*)d_in[3];
    const float* Whd = (const float*)d_in[4];
    const float* Wh2 = (const float*)d_in[5];
    const float* tp  = (const float*)d_in[6];
    const int* row = ei;
    const int* col = ei + E;

    size_t off = 0;
    auto alloc = [&](size_t bytes) -> void* {
        void* p = (char*)d_ws + off;
        off += (bytes + 255) & ~(size_t)255;
        return p;
    };
    int*   btail  = (int*)alloc((size_t)512 * 4);          // [0,NB) tails; [256],[257] barrier counters
    int*   bar1   = btail + 256;
    int*   bar2   = btail + 257;
    int*   deg    = (int*)alloc((size_t)N * 4);
    float* dinv   = (float*)alloc((size_t)N * 4);
    float* coeffs = (float*)alloc(KCHEB * 4);
    int*   kmaxp  = (int*)alloc(4);
    int*   ell    = (int*)alloc((size_t)N * 64 * 4);
    int2*  bucketArr = (int2*)alloc((size_t)NB * BCAP * 8);   // 8.0 MB
    unsigned short* xbf   = (unsigned short*)alloc(N64 * 2);
    unsigned short* xu    = (unsigned short*)alloc(UROW * 2);
    unsigned short* hidbf = (unsigned short*)alloc(N64 * 2);
    unsigned short* hidu  = (unsigned short*)alloc(UROW * 2);
    uint4* Wfrag1 = (uint4*)alloc(1024 * 16);
    uint4* Wfrag2 = (uint4*)alloc(512 * 16);
    size_t per_slot = N64 * 2 + UROW * 2 + 512;
    int nslots = (int)((ws_size - off) / per_slot);
    if (nslots > KCHEB - 1) nslots = KCHEB - 1;
    if (nslots < 3) nslots = 3;    // barrier path slot-aliasing requires >=3
    unsigned short* Tarr = (unsigned short*)alloc((size_t)nslots * N64 * 2);
    unsigned short* Uarr = (unsigned short*)alloc((size_t)nslots * UROW * 2);

    hipMemsetAsync(btail, 0, (size_t)512 * 4, stream);

    k1_bucket_conv_pack<<<ABLK + CONV_BLOCKS + 6, 256, 0, stream>>>(
        row, col, btail, bucketArr, (const float4*)x, (uint4*)xbf,
        Wd, Wh1, Whd, Wh2, Wfrag1, Wfrag2);
    k_ell<<<NB, 256, 0, stream>>>(bucketArr, btail, ell, deg);
    k2_node<<<XU_BLOCKS + PAD_BLOCKS + 2, 256, 0, stream>>>(
        x, deg, dinv, xu, ell, Uarr, hidu, nslots, tp, coeffs, kmaxp);

    const int mm_grid = (N + 63) / 64;

    // ---- heat phase 1 (persistent, normal launch, internal k-loop) ----
    spmm_phase<<<PHASE_GRID, 256, 0, stream>>>(deg, ell, xu, xbf,
                                               Tarr, Uarr, nslots, dinv, kmaxp, bar1);
    matmul_hidden<<<mm_grid, 256, 0, stream>>>(xbf, Tarr, nslots, coeffs, kmaxp,
                                               Wfrag1, hidbf, dinv, hidu);

    // ---- heat phase 2 ----
    spmm_phase<<<PHASE_GRID, 256, 0, stream>>>(deg, ell, hidu, hidbf,
                                               Tarr, Uarr, nslots, dinv, kmaxp, bar2);
    matmul_out<<<mm_grid, 256, 0, stream>>>(hidbf, Tarr, nslots, coeffs, kmaxp,
                                            Wfrag2, (float*)d_out);
}